// Round 16
// baseline (2206.141 us; speedup 1.0000x reference)
//
#include <hip/hip_runtime.h>

#define LNUM 6
#define EDIM 1024
#define HNUM 8
#define DHD  128
#define RNUM 33
#define FFD  4096
#define BNUM 8
#define SLEN 512
#define TOK  (BNUM*SLEN)   // 4096

typedef __attribute__((ext_vector_type(8))) short bf16x8;
typedef __attribute__((ext_vector_type(4))) float f32x4;
typedef unsigned short u16;
typedef unsigned int u32;

__device__ __forceinline__ u16 f2b(float f) {
  u32 u = __builtin_bit_cast(u32, f);
  u32 r = u + 0x7FFFu + ((u >> 16) & 1u);
  return (u16)(r >> 16);
}
__device__ __forceinline__ float b2f(u16 v) {
  return __builtin_bit_cast(float, ((u32)v) << 16);
}
__device__ __forceinline__ u32 pck(float a, float b) { return (u32)f2b(a) | ((u32)f2b(b) << 16); }

// async global->LDS, 16B per lane. LDS dest is wave-uniform base + lane*16.
#define GL16(gp, lp) __builtin_amdgcn_global_load_lds(                        \
    (const __attribute__((address_space(1))) void*)(gp),                      \
    (__attribute__((address_space(3))) void*)(lp), 16, 0, 0)

#define WAITVM16 do { asm volatile("s_waitcnt vmcnt(16)" ::: "memory"); \
                      __builtin_amdgcn_sched_barrier(0); } while (0)
#define WAITVM8 do { asm volatile("s_waitcnt vmcnt(8)" ::: "memory"); \
                     __builtin_amdgcn_sched_barrier(0); } while (0)
#define WAITVM4 do { asm volatile("s_waitcnt vmcnt(4)" ::: "memory"); \
                     __builtin_amdgcn_sched_barrier(0); } while (0)
#define WAITVM0 do { asm volatile("s_waitcnt vmcnt(0)" ::: "memory"); \
                     __builtin_amdgcn_sched_barrier(0); } while (0)

// ---------------- LayerNorm ----------------
template<int BF16OUT>
__global__ __launch_bounds__(256) void ln_kernel(const float* __restrict__ x,
                                                 const float* __restrict__ g,
                                                 const float* __restrict__ be,
                                                 void* __restrict__ o) {
  int row = blockIdx.x;
  int t = threadIdx.x;
  const float* xr = x + (size_t)row * EDIM;
  float4 xv = *reinterpret_cast<const float4*>(xr + t * 4);
  float s1 = xv.x + xv.y + xv.z + xv.w;
  float s2 = xv.x*xv.x + xv.y*xv.y + xv.z*xv.z + xv.w*xv.w;
#pragma unroll
  for (int off = 32; off >= 1; off >>= 1) {
    s1 += __shfl_down(s1, off, 64);
    s2 += __shfl_down(s2, off, 64);
  }
  __shared__ float r1[4], r2[4];
  if ((t & 63) == 0) { r1[t >> 6] = s1; r2[t >> 6] = s2; }
  __syncthreads();
  s1 = r1[0] + r1[1] + r1[2] + r1[3];
  s2 = r2[0] + r2[1] + r2[2] + r2[3];
  float mean = s1 * (1.0f / EDIM);
  float var  = s2 * (1.0f / EDIM) - mean * mean;
  float rstd = rsqrtf(var + 1e-5f);
  float4 gv = *reinterpret_cast<const float4*>(g + t * 4);
  float4 bv = *reinterpret_cast<const float4*>(be + t * 4);
  float o0 = (xv.x - mean) * rstd * gv.x + bv.x;
  float o1 = (xv.y - mean) * rstd * gv.y + bv.y;
  float o2 = (xv.z - mean) * rstd * gv.z + bv.z;
  float o3 = (xv.w - mean) * rstd * gv.w + bv.w;
  if (BF16OUT) {
    ushort4 ov; ov.x = f2b(o0); ov.y = f2b(o1); ov.z = f2b(o2); ov.w = f2b(o3);
    *reinterpret_cast<ushort4*>((u16*)o + (size_t)row * EDIM + t * 4) = ov;
  } else {
    *reinterpret_cast<float4*>((float*)o + (size_t)row * EDIM + t * 4) = make_float4(o0, o1, o2, o3);
  }
}

// ---------------- Weight transpose: f32 [Kd][Nd] -> bf16 [Nd][Kd] ----------------
__global__ __launch_bounds__(256) void wtrans(const float* __restrict__ src0,
                                              u16* __restrict__ dst0,
                                              int Kd, int Nd, size_t sstride, size_t dstride) {
  __shared__ float Ts[32][33];
  const float* src = src0 + blockIdx.z * sstride;
  u16* dst = dst0 + blockIdx.z * dstride;
  int r0 = blockIdx.y * 32, c0 = blockIdx.x * 32;
  int ty = threadIdx.x >> 3, tx = threadIdx.x & 7;
  float4 v = *reinterpret_cast<const float4*>(src + (size_t)(r0 + ty) * Nd + c0 + tx * 4);
  Ts[ty][tx*4+0] = v.x; Ts[ty][tx*4+1] = v.y; Ts[ty][tx*4+2] = v.z; Ts[ty][tx*4+3] = v.w;
  __syncthreads();
  ushort4 o;
  o.x = f2b(Ts[tx*4+0][ty]); o.y = f2b(Ts[tx*4+1][ty]);
  o.z = f2b(Ts[tx*4+2][ty]); o.w = f2b(Ts[tx*4+3][ty]);
  *reinterpret_cast<ushort4*>(dst + (size_t)(c0 + ty) * Kd + r0 + tx * 4) = o;
}

// ---------------- rel pack+transpose: int32 [b][i][j] -> u8 [b][j][i] ----------------
__global__ __launch_bounds__(256) void relpack(const int* __restrict__ rel,
                                               unsigned char* __restrict__ out) {
  __shared__ int Ts[32][33];
  int bz = blockIdx.z;
  int r0 = blockIdx.y * 32, c0 = blockIdx.x * 32;
  int ty = threadIdx.x >> 3, tx = threadIdx.x & 7;
  const int* src = rel + (size_t)bz * SLEN * SLEN;
  int4 v = *reinterpret_cast<const int4*>(src + (size_t)(r0 + ty) * SLEN + c0 + tx * 4);
  Ts[ty][tx*4+0] = v.x; Ts[ty][tx*4+1] = v.y; Ts[ty][tx*4+2] = v.z; Ts[ty][tx*4+3] = v.w;
  __syncthreads();
  u32 o = (u32)(Ts[tx*4+0][ty] & 255) | ((u32)(Ts[tx*4+1][ty] & 255) << 8) |
          ((u32)(Ts[tx*4+2][ty] & 255) << 16) | ((u32)(Ts[tx*4+3][ty] & 255) << 24);
  *reinterpret_cast<u32*>(out + (size_t)bz * SLEN * SLEN + (size_t)(c0 + ty) * SLEN + r0 + tx * 4) = o;
}

// ---------------- bf16 MFMA GEMM 128x128 (256 thr): C = A @ B^T ----------------
template<int DEPTH, int BIASMODE, int ACT, int RES, int OUTBF16>
__global__ __launch_bounds__(256) void gemm_bt(const u16* __restrict__ A,
                                               const u16* __restrict__ B,
                                               const float* __restrict__ bias0,
                                               const float* __restrict__ bias1,
                                               const float* __restrict__ res,
                                               void* __restrict__ Cv,
                                               int M, int N, int K) {
  __shared__ u16 As[DEPTH][128 * 64];
  __shared__ u16 Bs[DEPTH][128 * 64];
  int t = threadIdx.x;
  int l = t & 63, w = t >> 6;
  int wm = w & 1, wn = w >> 1;
  int m0 = blockIdx.y * 128, n0 = blockIdx.x * 128;
  f32x4 acc[4][4] = {};
  const u16* Agp = A + (size_t)(m0 + w * 32 + (l >> 3)) * K + (l & 7) * 8;
  const u16* Bgp = B + (size_t)(n0 + w * 32 + (l >> 3)) * K + (l & 7) * 8;
  const int nst = K >> 6;
  auto issue = [&](int k0, int bi) {
#pragma unroll
    for (int u = 0; u < 4; ++u) {
      GL16(Agp + (size_t)(u * 8) * K + k0, &As[bi][w * 2048 + u * 512]);
      GL16(Bgp + (size_t)(u * 8) * K + k0, &Bs[bi][w * 2048 + u * 512]);
    }
  };
  issue(0, 0);
  if (DEPTH == 3 && nst > 1) issue(64, 1);
  for (int i = 0; i < nst; ++i) {
    int cur = (DEPTH == 3) ? (i % 3) : (i & 1);
    if (DEPTH == 3) {
      if (i + 2 < nst)      { issue((i + 2) * 64, (i + 2) % 3); WAITVM16; }
      else if (i + 1 < nst) { WAITVM8; }
      else                  { WAITVM0; }
    } else {
      if (i + 1 < nst) { issue((i + 1) * 64, cur ^ 1); WAITVM8; }
      else             { WAITVM0; }
    }
    __builtin_amdgcn_s_barrier();
    const u16* Asc = As[cur];
    const u16* Bsc = Bs[cur];
#pragma unroll
    for (int d4 = 0; d4 < 2; ++d4) {
      bf16x8 af[4];
#pragma unroll
      for (int fm = 0; fm < 4; ++fm) {
        int row = wm * 64 + fm * 16 + (l & 15);
        af[fm] = *reinterpret_cast<const bf16x8*>(Asc + row * 64 + (d4 * 4 + (l >> 4)) * 8);
      }
#pragma unroll
      for (int fn = 0; fn < 4; ++fn) {
        int row = wn * 64 + fn * 16 + (l & 15);
        bf16x8 bf = *reinterpret_cast<const bf16x8*>(Bsc + row * 64 + (d4 * 4 + (l >> 4)) * 8);
#pragma unroll
        for (int fm = 0; fm < 4; ++fm)
          acc[fm][fn] = __builtin_amdgcn_mfma_f32_16x16x32_bf16(af[fm], bf, acc[fm][fn], 0, 0, 0);
      }
    }
    __builtin_amdgcn_s_barrier();
  }
#pragma unroll
  for (int fm = 0; fm < 4; ++fm)
#pragma unroll
    for (int fn = 0; fn < 4; ++fn)
#pragma unroll
      for (int e = 0; e < 4; ++e) {
        int m = m0 + wm * 64 + fm * 16 + (l >> 4) * 4 + e;
        int n = n0 + wn * 64 + fn * 16 + (l & 15);
        float v = acc[fm][fn][e];
        if (BIASMODE == 0) v += bias0[n];
        if (BIASMODE == 1) v += bias0[m];
        if (BIASMODE == 2) v += (n < 1024) ? bias0[n] : bias1[n - 1024];
        if (ACT == 1) v = fmaxf(v, 0.f);
        if (RES == 1) v += res[(size_t)m * N + n];
        if (OUTBF16) ((u16*)Cv)[(size_t)m * N + n] = f2b(v);
        else ((float*)Cv)[(size_t)m * N + n] = v;
      }
}

// ---------------- bf16 MFMA GEMM 256x256 (512 thr, 8 waves 2x4) — FFN1 ----------------
template<int BIASMODE, int ACT, int RES, int OUTBF16>
__global__ __launch_bounds__(512, 2) void gemm_big(const u16* __restrict__ A,
                                                   const u16* __restrict__ B,
                                                   const float* __restrict__ bias0,
                                                   const float* __restrict__ res,
                                                   void* __restrict__ Cv,
                                                   int M, int N, int K) {
  __shared__ u16 As[2][256 * 64];
  __shared__ u16 Bs[2][256 * 64];
  int t = threadIdx.x;
  int l = t & 63, w = t >> 6;      // w 0..7
  int wm = w >> 2, wn = w & 3;     // 2 x 4
  int m0 = blockIdx.y * 256, n0 = blockIdx.x * 256;
  f32x4 acc[8][4] = {};
  const u16* Agp = A + (size_t)(m0 + w * 32 + (l >> 3)) * K + (l & 7) * 8;
  const u16* Bgp = B + (size_t)(n0 + w * 32 + (l >> 3)) * K + (l & 7) * 8;
  const int nst = K >> 6;
  auto issue = [&](int k0, int bi) {
#pragma unroll
    for (int u = 0; u < 4; ++u) {
      GL16(Agp + (size_t)(u * 8) * K + k0, &As[bi][w * 2048 + u * 512]);
      GL16(Bgp + (size_t)(u * 8) * K + k0, &Bs[bi][w * 2048 + u * 512]);
    }
  };
  issue(0, 0);
  for (int i = 0; i < nst; ++i) {
    int cur = i & 1;
    if (i + 1 < nst) { issue((i + 1) * 64, cur ^ 1); WAITVM8; }
    else             { WAITVM0; }
    __builtin_amdgcn_s_barrier();
    const u16* Asc = As[cur];
    const u16* Bsc = Bs[cur];
#pragma unroll
    for (int d4 = 0; d4 < 2; ++d4) {
      bf16x8 bf[4];
#pragma unroll
      for (int fn = 0; fn < 4; ++fn) {
        int row = wn * 64 + fn * 16 + (l & 15);
        bf[fn] = *reinterpret_cast<const bf16x8*>(Bsc + row * 64 + (d4 * 4 + (l >> 4)) * 8);
      }
#pragma unroll
      for (int fm = 0; fm < 8; ++fm) {
        int row = wm * 128 + fm * 16 + (l & 15);
        bf16x8 af = *reinterpret_cast<const bf16x8*>(Asc + row * 64 + (d4 * 4 + (l >> 4)) * 8);
#pragma unroll
        for (int fn = 0; fn < 4; ++fn)
          acc[fm][fn] = __builtin_amdgcn_mfma_f32_16x16x32_bf16(af, bf[fn], acc[fm][fn], 0, 0, 0);
      }
    }
    __builtin_amdgcn_s_barrier();
  }
#pragma unroll
  for (int fm = 0; fm < 8; ++fm)
#pragma unroll
    for (int fn = 0; fn < 4; ++fn)
#pragma unroll
      for (int e = 0; e < 4; ++e) {
        int m = m0 + wm * 128 + fm * 16 + (l >> 4) * 4 + e;
        int n = n0 + wn * 64 + fn * 16 + (l & 15);
        float v = acc[fm][fn][e];
        if (BIASMODE == 0) v += bias0[n];
        if (ACT == 1) v = fmaxf(v, 0.f);
        if (RES == 1) v += res[(size_t)m * N + n];
        if (OUTBF16) ((u16*)Cv)[(size_t)m * N + n] = f2b(v);
        else ((float*)Cv)[(size_t)m * N + n] = v;
      }
}

// ---------------- Relational attention (flash, KVBLK=32, 4 blocks/CU) ----------
// LDS diet to 38.7KB -> 4 blocks/CU (16 waves/CU, was 2/8). Same pipeline template
// as R15, parameterized KVBLK 64->32: 16 tiles, 2 GL16/wave per tile, both counted
// waits = vmcnt(4) (queue: K(2), rel(2), V(2)). QR stored bf16. Epilogue relvT
// spans K+V buffers (16KB contiguous); extra barrier before out-stage overwrite.
#define A_P  0        // 8192 : K tile [32][128] swz (relk [48][128] spans P+Q in prologue)
#define A_Q  8192     // 8192 : V tile [128 d][32 j] swz
#define A_PS 16384    // 8192 : per-wave 2048B slabs: P[16][32] swz / arelB [16][64]
#define A_QR 24576    // 4608 : qr bf16 [64][36]
#define A_AR 29184    // 9216 : AREL f32 [64][36] (wave-private rows)
#define A_LS 38400    // 256  : LSUM f32 [64]
#define A_SM 38656

__global__ __launch_bounds__(256, 4) void attn_kernel(const u16* __restrict__ qk,
                                                      const u16* __restrict__ vt,
                                                      const unsigned char* __restrict__ rel8,
                                                      const int* __restrict__ lens,
                                                      const float* __restrict__ relk,
                                                      const float* __restrict__ relv,
                                                      u16* __restrict__ outb) {
  __align__(16) __shared__ char sm[A_SM];
  char*  Pb  = sm + A_P;
  char*  Qb  = sm + A_Q;
  char*  PSb = sm + A_PS;
  u16*   QRb = (u16*)(sm + A_QR);
  float* AREL = (float*)(sm + A_AR);
  float* LSUM = (float*)(sm + A_LS);

  const int t = threadIdx.x;
  const int l = t & 63, w = t >> 6;
  const int lg = l >> 4;        // 0..3
  const int ll = l & 15;        // 0..15
  const int bx = blockIdx.x;
  const int xcd = bx & 7, rem = bx >> 3, slot = rem & 7, it = rem >> 3;
  const int g = slot * 8 + xcd;
  const int b = g >> 3, hh = g & 7;
  const int i0 = it * 64;
  const int len = lens[b];
  const float scale = 0.08838834764831845f;
  char* PSw = PSb + w * 2048;

  // K tile [32 rows j][256B], 2 chunks/wave (chunk c=w*2+u covers rows c*4..c*4+4)
  auto issueK = [&](int kt) {
#pragma unroll
    for (int u = 0; u < 2; ++u) {
      int c = w * 2 + u;
      int row = c * 4 + lg;
      int sb = (ll * 16) ^ ((row & 7) << 4);
      const u16* gp = qk + (size_t)(b * SLEN + kt * 32 + row) * 2048 + 1024 + hh * DHD + (sb >> 1);
      GL16(gp, Pb + c * 1024);
    }
  };
  // V tile [128 rows d][64B], 2 chunks/wave (chunk c covers rows c*16..c*16+16)
  auto issueV = [&](int kt) {
#pragma unroll
    for (int u = 0; u < 2; ++u) {
      int c = w * 2 + u;
      int row = c * 16 + (l >> 2);
      int sb = ((l & 3) * 16) ^ (((l >> 2) & 3) << 4);
      const u16* gp = vt + (size_t)(hh * DHD + row) * TOK + b * SLEN + kt * 32 + (sb >> 1);
      GL16(gp, Qb + c * 1024);
    }
  };
  const unsigned char* relbase = rel8 + (size_t)b * SLEN * SLEN + (i0 + w * 16 + lg * 4);

  // ---- prologue ----
  for (int idx = l; idx < 16 * 36; idx += 64) AREL[w * 16 * 36 + idx] = 0.f;
  // relk bf16 [48][256B] swizzled, spans Pb..Pb+12288 (Pb and Qb contiguous)
  if (t < 192) {
    int r = t >> 2, sub = t & 3;
#pragma unroll
    for (int u = 0; u < 4; ++u) {
      int seg = sub * 4 + u;
      uint4 o;
      if (r < RNUM) {
        float4 f0 = *reinterpret_cast<const float4*>(relk + r * DHD + seg * 8);
        float4 f1 = *reinterpret_cast<const float4*>(relk + r * DHD + seg * 8 + 4);
        o.x = pck(f0.x, f0.y); o.y = pck(f0.z, f0.w);
        o.z = pck(f1.x, f1.y); o.w = pck(f1.z, f1.w);
      } else { o.x = o.y = o.z = o.w = 0u; }
      *reinterpret_cast<uint4*>(Pb + r * 256 + ((seg * 16) ^ ((r & 7) << 4))) = o;
    }
  }
  bf16x8 aq[4];
  {
    const u16* qrow = qk + (size_t)(b * SLEN + i0 + w * 16 + ll) * 2048 + hh * DHD;
#pragma unroll
    for (int d4 = 0; d4 < 4; ++d4)
      aq[d4] = *reinterpret_cast<const bf16x8*>(qrow + (d4 * 4 + lg) * 8);
  }
  __syncthreads();   // relk staged
#pragma unroll
  for (int rb = 0; rb < 3; ++rb) {
    f32x4 acc = {};
#pragma unroll
    for (int d4 = 0; d4 < 4; ++d4) {
      int rr = rb * 16 + ll;
      bf16x8 br = *reinterpret_cast<const bf16x8*>(Pb + rr * 256 + (((d4 * 4 + lg) * 16) ^ ((rr & 7) << 4)));
      acc = __builtin_amdgcn_mfma_f32_16x16x32_bf16(aq[d4], br, acc, 0, 0, 0);
    }
    int col = rb * 16 + ll;
    if (col < 36)
#pragma unroll
      for (int e = 0; e < 4; ++e)
        QRb[(w * 16 + lg * 4 + e) * 36 + col] = f2b(acc[e]);
  }
  __syncthreads();   // relk reads done; P/Q free (queue empty)
  issueK(0);         // queue: K0(2)
  u32 relw[2];
  {                  // rel(0) AFTER issueK(0): queue K0(2), rel0(2)
    const unsigned char* rb = relbase + (size_t)ll * SLEN;
#pragma unroll
    for (int fj = 0; fj < 2; ++fj)
      relw[fj] = *reinterpret_cast<const u32*>(rb + (size_t)(fj * 16) * SLEN);
  }

  bool rowv[4];
#pragma unroll
  for (int e = 0; e < 4; ++e) rowv[e] = (i0 + w * 16 + lg * 4 + e) < len;

  float m_[4];
#pragma unroll
  for (int e = 0; e < 4; ++e) m_[e] = -3.0e38f;
  f32x4 oacc[8] = {};

  for (int kt = 0; kt < 16; ++kt) {
    issueV(kt);                 // queue: K(kt)2, rel(kt)2, V(kt)2 = 6
    WAITVM4;                    // retire K(kt) only; rel+V stay in flight
    __builtin_amdgcn_s_barrier();
    __builtin_amdgcn_s_setprio(1);
    f32x4 sacc[2];
#pragma unroll
    for (int fj = 0; fj < 2; ++fj) {
      f32x4 a = {};
#pragma unroll
      for (int d4 = 0; d4 < 4; ++d4) {
        int row = fj * 16 + ll;
        bf16x8 bk_ = *reinterpret_cast<const bf16x8*>(Pb + row * 256 + (((d4 * 4 + lg) * 16) ^ ((row & 7) << 4)));
        a = __builtin_amdgcn_mfma_f32_16x16x32_bf16(aq[d4], bk_, a, 0, 0, 0);
      }
      sacc[fj] = a;
    }
    __builtin_amdgcn_s_setprio(0);
    // fixup (compiler inserts exact vmcnt before relw use; V stays in flight)
#pragma unroll
    for (int fj = 0; fj < 2; ++fj) {
      bool colv = (kt * 32 + fj * 16 + ll) < len;
      u32 rw = relw[fj];
#pragma unroll
      for (int e = 0; e < 4; ++e) {
        int r = (rw >> (8 * e)) & 255;
        float s = (sacc[fj][e] + b2f(QRb[(w * 16 + lg * 4 + e) * 36 + r])) * scale;
        s = (rowv[e] && colv) ? s : -1e9f;
        sacc[fj][e] = s;
      }
    }
    float pl[4];
#pragma unroll
    for (int e = 0; e < 4; ++e)
      pl[e] = fmaxf(sacc[0][e], sacc[1][e]);
    bool ok = (pl[0] <= m_[0] + 8.f) && (pl[1] <= m_[1] + 8.f) &&
              (pl[2] <= m_[2] + 8.f) && (pl[3] <= m_[3] + 8.f);
    if (!__all(ok)) {
#pragma unroll
      for (int e = 0; e < 4; ++e) {
        float px = pl[e];
        px = fmaxf(px, __shfl_xor(px, 1, 64));
        px = fmaxf(px, __shfl_xor(px, 2, 64));
        px = fmaxf(px, __shfl_xor(px, 4, 64));
        px = fmaxf(px, __shfl_xor(px, 8, 64));
        float mn = fmaxf(m_[e], px);
        float f = __expf(m_[e] - mn);
        m_[e] = mn;
#pragma unroll
        for (int fd = 0; fd < 8; ++fd) oacc[fd][e] *= f;
        if (f != 1.0f) {
          int row = w * 16 + lg * 4 + e;
          AREL[row * 36 + ll] *= f;
          AREL[row * 36 + 16 + ll] *= f;
          if (ll == 0) AREL[row * 36 + 32] *= f;
        }
      }
    }
#pragma unroll
    for (int fj = 0; fj < 2; ++fj) {
      u32 rw = relw[fj];
#pragma unroll
      for (int e = 0; e < 4; ++e) {
        float p = __expf(sacc[fj][e] - m_[e]);
        int iloc = lg * 4 + e;
        atomicAdd(&AREL[(w * 16 + iloc) * 36 + ((rw >> (8 * e)) & 255)], p);
        // P[16 rows][64B]: swizzle (row&3)<<4 (bijective within 64B row)
        *reinterpret_cast<u16*>(PSw + iloc * 64 + (((fj * 16 + ll) * 2) ^ ((iloc & 3) << 4))) = f2b(p);
      }
    }
    __builtin_amdgcn_s_barrier();   // K(kt) reads done
    if (kt < 15) {
      issueK(kt + 1);               // queue: V(kt)2, K(kt+1)2
      { // rel(kt+1) AFTER issueK: queue V(kt)2, K+1(2), rel+1(2) = 6
        const unsigned char* rb = relbase + (size_t)((kt + 1) * 32 + ll) * SLEN;
#pragma unroll
        for (int fj = 0; fj < 2; ++fj)
          relw[fj] = *reinterpret_cast<const u32*>(rb + (size_t)(fj * 16) * SLEN);
      }
      WAITVM4;                      // retire V(kt) only; K+rel stay in flight
    } else {
      WAITVM0;
    }
    __builtin_amdgcn_s_barrier();
    __builtin_amdgcn_s_setprio(1);
    { // PV: K-dim = 32 -> single MFMA per fd
      bf16x8 pa = *reinterpret_cast<const bf16x8*>(PSw + ll * 64 + ((lg * 16) ^ ((ll & 3) << 4)));
#pragma unroll
      for (int fd = 0; fd < 8; ++fd) {
        int row = fd * 16 + ll;
        bf16x8 vb = *reinterpret_cast<const bf16x8*>(Qb + row * 64 + ((lg * 16) ^ ((row & 3) << 4)));
        oacc[fd] = __builtin_amdgcn_mfma_f32_16x16x32_bf16(pa, vb, oacc[fd], 0, 0, 0);
      }
    }
    __builtin_amdgcn_s_setprio(0);
    __builtin_amdgcn_s_barrier();   // V(kt) reads done
  }
  // ---- epilogue ----
  if (l < 16) {
    int row = w * 16 + l;
    float s = 0.f;
    for (int r = 0; r < RNUM; ++r) s += AREL[row * 36 + r];
    LSUM[row] = s;
  }
#pragma unroll
  for (int e = 0; e < 4; ++e) {
    float inv = 1.0f / LSUM[w * 16 + lg * 4 + e];
#pragma unroll
    for (int fd = 0; fd < 8; ++fd) oacc[fd][e] *= inv;
  }
  // relvT bf16 [128 d][64 r] swizzled: spans Pb..Pb+16384 (P+V buffers)
  for (int idx = t; idx < 128 * 64; idx += 256) {
    int d = idx >> 6, r = idx & 63;
    u16 v = (r < RNUM) ? f2b(relv[r * DHD + d]) : (u16)0;
    *reinterpret_cast<u16*>(Pb + d * 128 + ((r * 2) ^ ((d & 7) << 4))) = v;
  }
  // arelB = AREL/l bf16 [16][64] (128B rows) in own 2048B slab
  for (int idx = l; idx < 1024; idx += 64) {
    int ri = idx >> 6, r = idx & 63;
    int row = w * 16 + ri;
    float v = (r < RNUM) ? AREL[row * 36 + r] * (1.0f / LSUM[row]) : 0.f;
    *reinterpret_cast<u16*>(PSw + ri * 128 + ((r * 2) ^ ((ri & 7) << 4))) = f2b(v);
  }
  __syncthreads();              // relvT ready
#pragma unroll
  for (int kc = 0; kc < 2; ++kc) {
    bf16x8 pa = *reinterpret_cast<const bf16x8*>(PSw + ll * 128 + (((kc * 4 + lg) * 16) ^ ((ll & 7) << 4)));
#pragma unroll
    for (int fd = 0; fd < 8; ++fd) {
      int row = fd * 16 + ll;
      bf16x8 vb = *reinterpret_cast<const bf16x8*>(Pb + row * 128 + (((kc * 4 + lg) * 16) ^ ((row & 7) << 4)));
      oacc[fd] = __builtin_amdgcn_mfma_f32_16x16x32_bf16(pa, vb, oacc[fd], 0, 0, 0);
    }
  }
  __syncthreads();              // all relvT reads done before out-stage overwrites span
  char* OSw = Pb + w * 4096;    // out-stage [16][128] bf16 = 4096B/wave in P+V span
#pragma unroll
  for (int fd = 0; fd < 8; ++fd)
#pragma unroll
    for (int e = 0; e < 4; ++e)
      *reinterpret_cast<u16*>(OSw + ((lg * 4 + e) * 128 + fd * 16 + ll) * 2) = f2b(oacc[fd][e]);
  __syncthreads();
  {
    int ri = l >> 2, q4 = l & 3;
    const char* srcb = OSw + ri * 256 + q4 * 64;
    u16* dst = outb + (size_t)(b * SLEN + i0 + w * 16 + ri) * EDIM + hh * DHD + q4 * 32;
    uint4 x0 = *reinterpret_cast<const uint4*>(srcb);
    uint4 x1 = *reinterpret_cast<const uint4*>(srcb + 16);
    uint4 x2 = *reinterpret_cast<const uint4*>(srcb + 32);
    uint4 x3 = *reinterpret_cast<const uint4*>(srcb + 48);
    *reinterpret_cast<uint4*>(dst)      = x0;
    *reinterpret_cast<uint4*>(dst + 8)  = x1;
    *reinterpret_cast<uint4*>(dst + 16) = x2;
    *reinterpret_cast<uint4*>(dst + 24) = x3;
  }
}

// ---------------- host ----------------
extern "C" void kernel_launch(void* const* d_in, const int* in_sizes, int n_in,
                              void* d_out, int out_size, void* d_ws, size_t ws_size,
                              hipStream_t stream) {
  const float* enc  = (const float*)d_in[0];
  const int*   rel  = (const int*)d_in[1];
  const int*   lens = (const int*)d_in[2];
  const float* Wq = (const float*)d_in[3];
  const float* bq = (const float*)d_in[4];
  const float* Wk = (const float*)d_in[5];
  const float* bk = (const float*)d_in[6];
  const float* Wv = (const float*)d_in[7];
  const float* bv = (const float*)d_in[8];
  const float* Wo = (const float*)d_in[9];
  const float* bo = (const float*)d_in[10];
  const float* relk = (const float*)d_in[11];
  const float* relv = (const float*)d_in[12];
  const float* W1 = (const float*)d_in[13];
  const float* b1 = (const float*)d_in[14];
  const float* W2 = (const float*)d_in[15];
  const float* b2 = (const float*)d_in[16];
  const float* ln1g = (const float*)d_in[17];
  const float* ln1b = (const float*)d_in[18];
  const float* ln2g = (const float*)d_in[19];
  const float* ln2b = (const float*)d_in[20];
  const float* lnfg = (const float*)d_in[21];
  const float* lnfb = (const float*)d_in[22];
  float* out = (float*)d_out;

  char* W = (char*)d_ws;
  u16* h     = (u16*)W;                                // 8 MB (dead during attn)
  unsigned char* rel8_h = (unsigned char*)W;           // fallback: alias of h
  char* U    = W + 8388608;
  u16* qkb   = (u16*)U;                                // 16 MB  [4096][2048]
  u16* vtb   = (u16*)(U + 16777216);                   // 8 MB   [1024][4096]
  u16* attno = (u16*)(U + 25165824);                   // 8 MB   [4096][1024]
  u16* mid   = (u16*)U;                                // 32 MB  (aliases qkb/vtb/attno)
  bool xin = ws_size >= (size_t)83886080;
  float* x = xin ? (float*)(W + 41943040) : out;
  size_t wt_off = xin ? 58720256 : 41943040;
  char* WT = W + wt_off;
  bool big = ws_size >= (size_t)209715200;

  const size_t EE = (size_t)EDIM * EDIM;      // 1M
  const size_t EF = (size_t)EDIM * FFD;       // 4M
  size_t wt_bytes = (big ? 6 : 1) * (size_t)(2*EE + EE + EE + EF + EF) * 2;
  bool rel_ded = ws_size >= wt_off + wt_bytes + (size_t)BNUM * SLEN * SLEN + 256;
  unsigned char* rel8 = rel_ded ? (unsigned char*)(WT + wt_bytes) : rel8_h;

  u16 *WqkT, *WvT, *WoT, *W1T, *W2T;
  dim3 blk(256);
  if (big) {
    u16* wqk_all = (u16*)WT;
    u16* wv_all  = wqk_all + 6 * 2 * EE;
    u16* wo_all  = wv_all + 6 * EE;
    u16* w1_all  = wo_all + 6 * EE;
    u16* w2_all  = w1_all + 6 * EF;
    wtrans<<<dim3(32, 32, 6), blk, 0, stream>>>(Wq, wqk_all, 1024, 1024, EE, 2 * EE);
    wtrans<<<dim3(32, 32, 6), blk, 0, stream>>>(Wk, wqk_all + EE, 1024, 1024, EE, 2 * EE);
    wtrans<<<dim3(32, 32, 6), blk, 0, stream>>>(Wv, wv_all, 1024, 1024, EE, EE);
    wtrans<<<dim3(32, 32, 6), blk, 0, stream>>>(Wo, wo_all, 1024, 1024, EE, EE);
    wtrans<<<dim3(128, 32, 6), blk, 0, stream>>>(W1, w1_all, 1024, 4096, EF, EF);
    wtrans<<<dim3(32, 128, 6), blk, 0, stream>>>(W2, w2_all, 4096, 1024, EF, EF);
    WqkT = wqk_all; WvT = wv_all; WoT = wo_all; W1T = w1_all; W2T = w2_all;
  } else {
    WqkT = (u16*)WT;
    WvT  = WqkT + 2 * EE;
    WoT  = WvT + EE;
    W1T  = WoT + EE;
    W2T  = W1T + EF;
  }
  if (rel_ded) relpack<<<dim3(16, 16, 8), blk, 0, stream>>>(rel, rel8);

  dim3 gLN(TOK);
  for (int ll = 0; ll < LNUM; ++ll) {
    u16 *wqkT, *wvT, *woT, *w1T, *w2T;
    if (big) {
      wqkT = WqkT + (size_t)ll * 2 * EE; wvT = WvT + (size_t)ll * EE; woT = WoT + (size_t)ll * EE;
      w1T = W1T + (size_t)ll * EF; w2T = W2T + (size_t)ll * EF;
    } else {
      wqkT = WqkT; wvT = WvT; woT = WoT; w1T = W1T; w2T = W2T;
      wtrans<<<dim3(32, 32, 1), blk, 0, stream>>>(Wq + ll * EE, wqkT, 1024, 1024, 0, 0);
      wtrans<<<dim3(32, 32, 1), blk, 0, stream>>>(Wk + ll * EE, wqkT + EE, 1024, 1024, 0, 0);
      wtrans<<<dim3(32, 32, 1), blk, 0, stream>>>(Wv + ll * EE, wvT, 1024, 1024, 0, 0);
      wtrans<<<dim3(32, 32, 1), blk, 0, stream>>>(Wo + ll * EE, woT, 1024, 1024, 0, 0);
      wtrans<<<dim3(128, 32, 1), blk, 0, stream>>>(W1 + ll * EF, w1T, 1024, 4096, 0, 0);
      wtrans<<<dim3(32, 128, 1), blk, 0, stream>>>(W2 + ll * EF, w2T, 4096, 1024, 0, 0);
    }
    const float* xin_p = (ll == 0) ? enc : x;
    ln_kernel<1><<<gLN, blk, 0, stream>>>(xin_p, ln1g + ll * EDIM, ln1b + ll * EDIM, h);
    gemm_bt<2, 2, 0, 0, 1><<<dim3(16, 32), blk, 0, stream>>>(h, wqkT, bq + ll * EDIM, bk + ll * EDIM,
                                                             nullptr, qkb, TOK, 2048, EDIM);
    gemm_bt<3, 1, 0, 0, 1><<<dim3(32, 8), blk, 0, stream>>>(wvT, h, bv + ll * EDIM, nullptr,
                                                            nullptr, vtb, EDIM, TOK, EDIM);
    if (!rel_ded) relpack<<<dim3(16, 16, 8), blk, 0, stream>>>(rel, rel8);
    attn_kernel<<<dim3(512), blk, 0, stream>>>(qkb, vtb, rel8, lens,
                                               relk + (size_t)ll * RNUM * DHD,
                                               relv + (size_t)ll * RNUM * DHD, attno);
    gemm_bt<3, 0, 0, 1, 0><<<dim3(8, 32), blk, 0, stream>>>(attno, woT, bo + ll * EDIM, nullptr,
                                                            xin_p, x, TOK, EDIM, EDIM);
    ln_kernel<1><<<gLN, blk, 0, stream>>>(x, ln2g + ll * EDIM, ln2b + ll * EDIM, h);
    gemm_big<0, 1, 0, 1><<<dim3(FFD / 256, TOK / 256), dim3(512), 0, stream>>>(
        h, w1T, b1 + ll * FFD, nullptr, mid, TOK, FFD, EDIM);
    gemm_bt<3, 0, 0, 1, 0><<<dim3(8, 32), blk, 0, stream>>>(mid, w2T, b2 + ll * EDIM, nullptr,
                                                            x, x, TOK, EDIM, FFD);
  }
  ln_kernel<0><<<gLN, blk, 0, stream>>>(x, lnfg, lnfb, out);
}

// Round 17
// 2155.955 us; speedup vs baseline: 1.0233x; 1.0233x over previous
//
#include <hip/hip_runtime.h>

#define LNUM 6
#define EDIM 1024
#define HNUM 8
#define DHD  128
#define RNUM 33
#define FFD  4096
#define BNUM 8
#define SLEN 512
#define TOK  (BNUM*SLEN)   // 4096

typedef __attribute__((ext_vector_type(8))) short bf16x8;
typedef __attribute__((ext_vector_type(4))) float f32x4;
typedef unsigned short u16;
typedef unsigned int u32;

__device__ __forceinline__ u16 f2b(float f) {
  u32 u = __builtin_bit_cast(u32, f);
  u32 r = u + 0x7FFFu + ((u >> 16) & 1u);
  return (u16)(r >> 16);
}
__device__ __forceinline__ u32 pck(float a, float b) { return (u32)f2b(a) | ((u32)f2b(b) << 16); }

// async global->LDS, 16B per lane. LDS dest is wave-uniform base + lane*16.
#define GL16(gp, lp) __builtin_amdgcn_global_load_lds(                        \
    (const __attribute__((address_space(1))) void*)(gp),                      \
    (__attribute__((address_space(3))) void*)(lp), 16, 0, 0)

#define WAITVM20 do { asm volatile("s_waitcnt vmcnt(20)" ::: "memory"); \
                      __builtin_amdgcn_sched_barrier(0); } while (0)
#define WAITVM16 do { asm volatile("s_waitcnt vmcnt(16)" ::: "memory"); \
                      __builtin_amdgcn_sched_barrier(0); } while (0)
#define WAITVM8 do { asm volatile("s_waitcnt vmcnt(8)" ::: "memory"); \
                     __builtin_amdgcn_sched_barrier(0); } while (0)
#define WAITVM0 do { asm volatile("s_waitcnt vmcnt(0)" ::: "memory"); \
                     __builtin_amdgcn_sched_barrier(0); } while (0)

// ---------------- LayerNorm ----------------
template<int BF16OUT>
__global__ __launch_bounds__(256) void ln_kernel(const float* __restrict__ x,
                                                 const float* __restrict__ g,
                                                 const float* __restrict__ be,
                                                 void* __restrict__ o) {
  int row = blockIdx.x;
  int t = threadIdx.x;
  const float* xr = x + (size_t)row * EDIM;
  float4 xv = *reinterpret_cast<const float4*>(xr + t * 4);
  float s1 = xv.x + xv.y + xv.z + xv.w;
  float s2 = xv.x*xv.x + xv.y*xv.y + xv.z*xv.z + xv.w*xv.w;
#pragma unroll
  for (int off = 32; off >= 1; off >>= 1) {
    s1 += __shfl_down(s1, off, 64);
    s2 += __shfl_down(s2, off, 64);
  }
  __shared__ float r1[4], r2[4];
  if ((t & 63) == 0) { r1[t >> 6] = s1; r2[t >> 6] = s2; }
  __syncthreads();
  s1 = r1[0] + r1[1] + r1[2] + r1[3];
  s2 = r2[0] + r2[1] + r2[2] + r2[3];
  float mean = s1 * (1.0f / EDIM);
  float var  = s2 * (1.0f / EDIM) - mean * mean;
  float rstd = rsqrtf(var + 1e-5f);
  float4 gv = *reinterpret_cast<const float4*>(g + t * 4);
  float4 bv = *reinterpret_cast<const float4*>(be + t * 4);
  float o0 = (xv.x - mean) * rstd * gv.x + bv.x;
  float o1 = (xv.y - mean) * rstd * gv.y + bv.y;
  float o2 = (xv.z - mean) * rstd * gv.z + bv.z;
  float o3 = (xv.w - mean) * rstd * gv.w + bv.w;
  if (BF16OUT) {
    ushort4 ov; ov.x = f2b(o0); ov.y = f2b(o1); ov.z = f2b(o2); ov.w = f2b(o3);
    *reinterpret_cast<ushort4*>((u16*)o + (size_t)row * EDIM + t * 4) = ov;
  } else {
    *reinterpret_cast<float4*>((float*)o + (size_t)row * EDIM + t * 4) = make_float4(o0, o1, o2, o3);
  }
}

// ---------------- Weight transpose: f32 [Kd][Nd] -> bf16 [Nd][Kd] ----------------
__global__ __launch_bounds__(256) void wtrans(const float* __restrict__ src0,
                                              u16* __restrict__ dst0,
                                              int Kd, int Nd, size_t sstride, size_t dstride) {
  __shared__ float Ts[32][33];
  const float* src = src0 + blockIdx.z * sstride;
  u16* dst = dst0 + blockIdx.z * dstride;
  int r0 = blockIdx.y * 32, c0 = blockIdx.x * 32;
  int ty = threadIdx.x >> 3, tx = threadIdx.x & 7;
  float4 v = *reinterpret_cast<const float4*>(src + (size_t)(r0 + ty) * Nd + c0 + tx * 4);
  Ts[ty][tx*4+0] = v.x; Ts[ty][tx*4+1] = v.y; Ts[ty][tx*4+2] = v.z; Ts[ty][tx*4+3] = v.w;
  __syncthreads();
  ushort4 o;
  o.x = f2b(Ts[tx*4+0][ty]); o.y = f2b(Ts[tx*4+1][ty]);
  o.z = f2b(Ts[tx*4+2][ty]); o.w = f2b(Ts[tx*4+3][ty]);
  *reinterpret_cast<ushort4*>(dst + (size_t)(c0 + ty) * Kd + r0 + tx * 4) = o;
}

// ---------------- rel pack+transpose: int32 [b][i][j] -> u8 [b][j][i] ----------------
__global__ __launch_bounds__(256) void relpack(const int* __restrict__ rel,
                                               unsigned char* __restrict__ out) {
  __shared__ int Ts[32][33];
  int bz = blockIdx.z;
  int r0 = blockIdx.y * 32, c0 = blockIdx.x * 32;
  int ty = threadIdx.x >> 3, tx = threadIdx.x & 7;
  const int* src = rel + (size_t)bz * SLEN * SLEN;
  int4 v = *reinterpret_cast<const int4*>(src + (size_t)(r0 + ty) * SLEN + c0 + tx * 4);
  Ts[ty][tx*4+0] = v.x; Ts[ty][tx*4+1] = v.y; Ts[ty][tx*4+2] = v.z; Ts[ty][tx*4+3] = v.w;
  __syncthreads();
  u32 o = (u32)(Ts[tx*4+0][ty] & 255) | ((u32)(Ts[tx*4+1][ty] & 255) << 8) |
          ((u32)(Ts[tx*4+2][ty] & 255) << 16) | ((u32)(Ts[tx*4+3][ty] & 255) << 24);
  *reinterpret_cast<u32*>(out + (size_t)bz * SLEN * SLEN + (size_t)(c0 + ty) * SLEN + r0 + tx * 4) = o;
}

// ---------------- bf16 MFMA GEMM 128x128 (256 thr): C = A @ B^T ----------------
// DEPTH=3 (vmcnt(16)) for 1-block/CU dispatches; DEPTH=2 (vmcnt(8)) for QK.
template<int DEPTH, int BIASMODE, int ACT, int RES, int OUTBF16>
__global__ __launch_bounds__(256) void gemm_bt(const u16* __restrict__ A,
                                               const u16* __restrict__ B,
                                               const float* __restrict__ bias0,
                                               const float* __restrict__ bias1,
                                               const float* __restrict__ res,
                                               void* __restrict__ Cv,
                                               int M, int N, int K) {
  __shared__ u16 As[DEPTH][128 * 64];
  __shared__ u16 Bs[DEPTH][128 * 64];
  int t = threadIdx.x;
  int l = t & 63, w = t >> 6;
  int wm = w & 1, wn = w >> 1;
  int m0 = blockIdx.y * 128, n0 = blockIdx.x * 128;
  f32x4 acc[4][4] = {};
  const u16* Agp = A + (size_t)(m0 + w * 32 + (l >> 3)) * K + (l & 7) * 8;
  const u16* Bgp = B + (size_t)(n0 + w * 32 + (l >> 3)) * K + (l & 7) * 8;
  const int nst = K >> 6;
  auto issue = [&](int k0, int bi) {
#pragma unroll
    for (int u = 0; u < 4; ++u) {
      GL16(Agp + (size_t)(u * 8) * K + k0, &As[bi][w * 2048 + u * 512]);
      GL16(Bgp + (size_t)(u * 8) * K + k0, &Bs[bi][w * 2048 + u * 512]);
    }
  };
  issue(0, 0);
  if (DEPTH == 3 && nst > 1) issue(64, 1);
  for (int i = 0; i < nst; ++i) {
    int cur = (DEPTH == 3) ? (i % 3) : (i & 1);
    if (DEPTH == 3) {
      if (i + 2 < nst)      { issue((i + 2) * 64, (i + 2) % 3); WAITVM16; }
      else if (i + 1 < nst) { WAITVM8; }
      else                  { WAITVM0; }
    } else {
      if (i + 1 < nst) { issue((i + 1) * 64, cur ^ 1); WAITVM8; }
      else             { WAITVM0; }
    }
    __builtin_amdgcn_s_barrier();
    const u16* Asc = As[cur];
    const u16* Bsc = Bs[cur];
#pragma unroll
    for (int d4 = 0; d4 < 2; ++d4) {
      bf16x8 af[4];
#pragma unroll
      for (int fm = 0; fm < 4; ++fm) {
        int row = wm * 64 + fm * 16 + (l & 15);
        af[fm] = *reinterpret_cast<const bf16x8*>(Asc + row * 64 + (d4 * 4 + (l >> 4)) * 8);
      }
#pragma unroll
      for (int fn = 0; fn < 4; ++fn) {
        int row = wn * 64 + fn * 16 + (l & 15);
        bf16x8 bf = *reinterpret_cast<const bf16x8*>(Bsc + row * 64 + (d4 * 4 + (l >> 4)) * 8);
#pragma unroll
        for (int fm = 0; fm < 4; ++fm)
          acc[fm][fn] = __builtin_amdgcn_mfma_f32_16x16x32_bf16(af[fm], bf, acc[fm][fn], 0, 0, 0);
      }
    }
    __builtin_amdgcn_s_barrier();
  }
#pragma unroll
  for (int fm = 0; fm < 4; ++fm)
#pragma unroll
    for (int fn = 0; fn < 4; ++fn)
#pragma unroll
      for (int e = 0; e < 4; ++e) {
        int m = m0 + wm * 64 + fm * 16 + (l >> 4) * 4 + e;
        int n = n0 + wn * 64 + fn * 16 + (l & 15);
        float v = acc[fm][fn][e];
        if (BIASMODE == 0) v += bias0[n];
        if (BIASMODE == 1) v += bias0[m];
        if (BIASMODE == 2) v += (n < 1024) ? bias0[n] : bias1[n - 1024];
        if (ACT == 1) v = fmaxf(v, 0.f);
        if (RES == 1) v += res[(size_t)m * N + n];
        if (OUTBF16) ((u16*)Cv)[(size_t)m * N + n] = f2b(v);
        else ((float*)Cv)[(size_t)m * N + n] = v;
      }
}

// ---------------- bf16 MFMA GEMM 256x256 (512 thr, 8 waves 2x4) — FFN1 ----------------
template<int BIASMODE, int ACT, int RES, int OUTBF16>
__global__ __launch_bounds__(512, 2) void gemm_big(const u16* __restrict__ A,
                                                   const u16* __restrict__ B,
                                                   const float* __restrict__ bias0,
                                                   const float* __restrict__ res,
                                                   void* __restrict__ Cv,
                                                   int M, int N, int K) {
  __shared__ u16 As[2][256 * 64];
  __shared__ u16 Bs[2][256 * 64];
  int t = threadIdx.x;
  int l = t & 63, w = t >> 6;      // w 0..7
  int wm = w >> 2, wn = w & 3;     // 2 x 4
  int m0 = blockIdx.y * 256, n0 = blockIdx.x * 256;
  f32x4 acc[8][4] = {};
  const u16* Agp = A + (size_t)(m0 + w * 32 + (l >> 3)) * K + (l & 7) * 8;
  const u16* Bgp = B + (size_t)(n0 + w * 32 + (l >> 3)) * K + (l & 7) * 8;
  const int nst = K >> 6;
  auto issue = [&](int k0, int bi) {
#pragma unroll
    for (int u = 0; u < 4; ++u) {
      GL16(Agp + (size_t)(u * 8) * K + k0, &As[bi][w * 2048 + u * 512]);
      GL16(Bgp + (size_t)(u * 8) * K + k0, &Bs[bi][w * 2048 + u * 512]);
    }
  };
  issue(0, 0);
  for (int i = 0; i < nst; ++i) {
    int cur = i & 1;
    if (i + 1 < nst) { issue((i + 1) * 64, cur ^ 1); WAITVM8; }
    else             { WAITVM0; }
    __builtin_amdgcn_s_barrier();
    const u16* Asc = As[cur];
    const u16* Bsc = Bs[cur];
#pragma unroll
    for (int d4 = 0; d4 < 2; ++d4) {
      bf16x8 bf[4];
#pragma unroll
      for (int fn = 0; fn < 4; ++fn) {
        int row = wn * 64 + fn * 16 + (l & 15);
        bf[fn] = *reinterpret_cast<const bf16x8*>(Bsc + row * 64 + (d4 * 4 + (l >> 4)) * 8);
      }
#pragma unroll
      for (int fm = 0; fm < 8; ++fm) {
        int row = wm * 128 + fm * 16 + (l & 15);
        bf16x8 af = *reinterpret_cast<const bf16x8*>(Asc + row * 64 + (d4 * 4 + (l >> 4)) * 8);
#pragma unroll
        for (int fn = 0; fn < 4; ++fn)
          acc[fm][fn] = __builtin_amdgcn_mfma_f32_16x16x32_bf16(af, bf[fn], acc[fm][fn], 0, 0, 0);
      }
    }
    __builtin_amdgcn_s_barrier();
  }
#pragma unroll
  for (int fm = 0; fm < 8; ++fm)
#pragma unroll
    for (int fn = 0; fn < 4; ++fn)
#pragma unroll
      for (int e = 0; e < 4; ++e) {
        int m = m0 + wm * 128 + fm * 16 + (l >> 4) * 4 + e;
        int n = n0 + wn * 64 + fn * 16 + (l & 15);
        float v = acc[fm][fn][e];
        if (BIASMODE == 0) v += bias0[n];
        if (ACT == 1) v = fmaxf(v, 0.f);
        if (RES == 1) v += res[(size_t)m * N + n];
        if (OUTBF16) ((u16*)Cv)[(size_t)m * N + n] = f2b(v);
        else ((float*)Cv)[(size_t)m * N + n] = v;
      }
}

// ---------------- Relational attention (flash, GL16-pipelined, defer-max) ----------
// vmcnt queue is ORDERED: per tile issue order is K(prev), rel(prev), V -> exact
// waits are vmcnt(20) at both sync points (retire only the oldest 4 K/V loads; the
// 16 rel gathers + younger tile loads stay in flight; the fixup's compiler-inserted
// vmcnt drains rel exactly when consumed). rel prefetch moved AFTER issueK.
#define A_P  0        // 16384: relk[48][128] swz -> K tile [64][128] swz -> relvT [128][64]
#define A_Q  16384    // 16384: V tile [128 d][64 j] swz -> out-stage [4 waves][16][128]
#define A_PS 32768    // 8192 : per-wave 2048B slabs: P[16][64] swz / arelB [16][64]
#define A_QR 40960    // 9216 : qr f32 [64][36]
#define A_AR 50176    // 9216 : AREL f32 [64][36] (wave-private rows)
#define A_LS 59392    // 256  : LSUM f32 [64]
#define A_SM 59648

__global__ __launch_bounds__(256, 2) void attn_kernel(const u16* __restrict__ qk,
                                                      const u16* __restrict__ vt,
                                                      const unsigned char* __restrict__ rel8,
                                                      const int* __restrict__ lens,
                                                      const float* __restrict__ relk,
                                                      const float* __restrict__ relv,
                                                      u16* __restrict__ outb) {
  __align__(16) __shared__ char sm[A_SM];
  char*  Pb  = sm + A_P;
  char*  Qb  = sm + A_Q;
  char*  PSb = sm + A_PS;
  float* QR  = (float*)(sm + A_QR);
  float* AREL = (float*)(sm + A_AR);
  float* LSUM = (float*)(sm + A_LS);

  const int t = threadIdx.x;
  const int l = t & 63, w = t >> 6;
  const int lg = l >> 4;        // 0..3
  const int ll = l & 15;        // 0..15
  const int bx = blockIdx.x;
  const int xcd = bx & 7, rem = bx >> 3, slot = rem & 7, it = rem >> 3;
  const int g = slot * 8 + xcd;
  const int b = g >> 3, hh = g & 7;
  const int i0 = it * 64;
  const int len = lens[b];
  const float scale = 0.08838834764831845f;
  char* PSw = PSb + w * 2048;

  auto issueK = [&](int kt) {
#pragma unroll
    for (int u = 0; u < 4; ++u) {
      int row = w * 16 + u * 4 + (lg);
      int sb = (ll * 16) ^ (((u * 4 + lg) & 7) << 4);
      const u16* gp = qk + (size_t)(b * SLEN + kt * 64 + row) * 2048 + 1024 + hh * DHD + (sb >> 1);
      GL16(gp, Pb + (w * 4 + u) * 1024);
    }
  };
  auto issueV = [&](int kt) {
#pragma unroll
    for (int u = 0; u < 4; ++u) {
      int row = w * 32 + u * 8 + (l >> 3);
      int sb = ((l & 7) * 16) ^ ((l >> 3) << 4);
      const u16* gp = vt + (size_t)(hh * DHD + row) * TOK + b * SLEN + kt * 64 + (sb >> 1);
      GL16(gp, Qb + (w * 4 + u) * 1024);
    }
  };
  const unsigned char* relbase = rel8 + (size_t)b * SLEN * SLEN + (i0 + w * 16 + lg * 4);

  // ---- prologue ----
  for (int idx = l; idx < 16 * 36; idx += 64) AREL[w * 16 * 36 + idx] = 0.f;
  if (t < 192) {
    int r = t >> 2, sub = t & 3;
#pragma unroll
    for (int u = 0; u < 4; ++u) {
      int seg = sub * 4 + u;
      uint4 o;
      if (r < RNUM) {
        float4 f0 = *reinterpret_cast<const float4*>(relk + r * DHD + seg * 8);
        float4 f1 = *reinterpret_cast<const float4*>(relk + r * DHD + seg * 8 + 4);
        o.x = pck(f0.x, f0.y); o.y = pck(f0.z, f0.w);
        o.z = pck(f1.x, f1.y); o.w = pck(f1.z, f1.w);
      } else { o.x = o.y = o.z = o.w = 0u; }
      *reinterpret_cast<uint4*>(Pb + r * 256 + ((seg * 16) ^ ((r & 7) << 4))) = o;
    }
  }
  bf16x8 aq[4];
  {
    const u16* qrow = qk + (size_t)(b * SLEN + i0 + w * 16 + ll) * 2048 + hh * DHD;
#pragma unroll
    for (int d4 = 0; d4 < 4; ++d4)
      aq[d4] = *reinterpret_cast<const bf16x8*>(qrow + (d4 * 4 + lg) * 8);
  }
  __syncthreads();   // relk staged
#pragma unroll
  for (int rb = 0; rb < 3; ++rb) {
    f32x4 acc = {};
#pragma unroll
    for (int d4 = 0; d4 < 4; ++d4) {
      int rr = rb * 16 + ll;
      bf16x8 br = *reinterpret_cast<const bf16x8*>(Pb + rr * 256 + (((d4 * 4 + lg) * 16) ^ ((rr & 7) << 4)));
      acc = __builtin_amdgcn_mfma_f32_16x16x32_bf16(aq[d4], br, acc, 0, 0, 0);
    }
    int col = rb * 16 + ll;
    if (col < 36)
#pragma unroll
      for (int e = 0; e < 4; ++e)
        QR[(w * 16 + lg * 4 + e) * 36 + col] = acc[e];
  }
  __syncthreads();   // relk reads done; P free (queue empty here)
  issueK(0);         // queue: K0(4)
  u32 relw[4];
  {                  // rel(0) AFTER issueK(0): queue K0(4), rel0(16)
    const unsigned char* rb = relbase + (size_t)ll * SLEN;
#pragma unroll
    for (int fj = 0; fj < 4; ++fj)
      relw[fj] = *reinterpret_cast<const u32*>(rb + (size_t)(fj * 16) * SLEN);
  }

  bool rowv[4];
#pragma unroll
  for (int e = 0; e < 4; ++e) rowv[e] = (i0 + w * 16 + lg * 4 + e) < len;

  float m_[4];
#pragma unroll
  for (int e = 0; e < 4; ++e) m_[e] = -3.0e38f;
  f32x4 oacc[8] = {};

  for (int kt = 0; kt < 8; ++kt) {
    issueV(kt);                 // queue: K(kt)4, rel(kt)16, V(kt)4 = 24
    WAITVM20;                   // retire K(kt) only; rel+V stay in flight
    __builtin_amdgcn_s_barrier();
    __builtin_amdgcn_s_setprio(1);
    f32x4 sacc[4];
#pragma unroll
    for (int fj = 0; fj < 4; ++fj) {
      f32x4 a = {};
#pragma unroll
      for (int d4 = 0; d4 < 4; ++d4) {
        int row = fj * 16 + ll;
        bf16x8 bk_ = *reinterpret_cast<const bf16x8*>(Pb + row * 256 + (((d4 * 4 + lg) * 16) ^ ((row & 7) << 4)));
        a = __builtin_amdgcn_mfma_f32_16x16x32_bf16(aq[d4], bk_, a, 0, 0, 0);
      }
      sacc[fj] = a;
    }
    __builtin_amdgcn_s_setprio(0);
    // fixup (compiler inserts exact vmcnt before relw use; V stays in flight)
#pragma unroll
    for (int fj = 0; fj < 4; ++fj) {
      bool colv = (kt * 64 + fj * 16 + ll) < len;
      u32 rw = relw[fj];
#pragma unroll
      for (int e = 0; e < 4; ++e) {
        int r = (rw >> (8 * e)) & 255;
        float s = (sacc[fj][e] + QR[(w * 16 + lg * 4 + e) * 36 + r]) * scale;
        s = (rowv[e] && colv) ? s : -1e9f;
        sacc[fj][e] = s;
      }
    }
    float pl[4];
#pragma unroll
    for (int e = 0; e < 4; ++e)
      pl[e] = fmaxf(fmaxf(sacc[0][e], sacc[1][e]), fmaxf(sacc[2][e], sacc[3][e]));
    bool ok = (pl[0] <= m_[0] + 8.f) && (pl[1] <= m_[1] + 8.f) &&
              (pl[2] <= m_[2] + 8.f) && (pl[3] <= m_[3] + 8.f);
    if (!__all(ok)) {
#pragma unroll
      for (int e = 0; e < 4; ++e) {
        float px = pl[e];
        px = fmaxf(px, __shfl_xor(px, 1, 64));
        px = fmaxf(px, __shfl_xor(px, 2, 64));
        px = fmaxf(px, __shfl_xor(px, 4, 64));
        px = fmaxf(px, __shfl_xor(px, 8, 64));
        float mn = fmaxf(m_[e], px);
        float f = __expf(m_[e] - mn);
        m_[e] = mn;
#pragma unroll
        for (int fd = 0; fd < 8; ++fd) oacc[fd][e] *= f;
        if (f != 1.0f) {
          int row = w * 16 + lg * 4 + e;
          AREL[row * 36 + ll] *= f;
          AREL[row * 36 + 16 + ll] *= f;
          if (ll == 0) AREL[row * 36 + 32] *= f;
        }
      }
    }
#pragma unroll
    for (int fj = 0; fj < 4; ++fj) {
      u32 rw = relw[fj];
#pragma unroll
      for (int e = 0; e < 4; ++e) {
        float p = __expf(sacc[fj][e] - m_[e]);
        int iloc = lg * 4 + e;
        atomicAdd(&AREL[(w * 16 + iloc) * 36 + ((rw >> (8 * e)) & 255)], p);
        *reinterpret_cast<u16*>(PSw + iloc * 128 + (((fj * 16 + ll) * 2) ^ ((iloc & 7) << 4))) = f2b(p);
      }
    }
    __builtin_amdgcn_s_barrier();   // K(kt) reads done
    if (kt < 7) {
      issueK(kt + 1);               // queue: V(kt)4, K(kt+1)4
      { // rel(kt+1) AFTER issueK: queue V(kt)4, K(kt+1)4, rel(kt+1)16 = 24
        const unsigned char* rb = relbase + (size_t)((kt + 1) * 64 + ll) * SLEN;
#pragma unroll
        for (int fj = 0; fj < 4; ++fj)
          relw[fj] = *reinterpret_cast<const u32*>(rb + (size_t)(fj * 16) * SLEN);
      }
      WAITVM20;                     // retire V(kt) only; K+rel stay in flight
    } else {
      WAITVM0;
    }
    __builtin_amdgcn_s_barrier();
    __builtin_amdgcn_s_setprio(1);
#pragma unroll
    for (int kc = 0; kc < 2; ++kc) {
      bf16x8 pa = *reinterpret_cast<const bf16x8*>(PSw + ll * 128 + (((kc * 4 + lg) * 16) ^ ((ll & 7) << 4)));
#pragma unroll
      for (int fd = 0; fd < 8; ++fd) {
        int row = fd * 16 + ll;
        bf16x8 vb = *reinterpret_cast<const bf16x8*>(Qb + row * 128 + (((kc * 4 + lg) * 16) ^ ((row & 7) << 4)));
        oacc[fd] = __builtin_amdgcn_mfma_f32_16x16x32_bf16(pa, vb, oacc[fd], 0, 0, 0);
      }
    }
    __builtin_amdgcn_s_setprio(0);
    __builtin_amdgcn_s_barrier();   // V(kt) reads done
  }
  // ---- epilogue ----
  if (l < 16) {
    int row = w * 16 + l;
    float s = 0.f;
    for (int r = 0; r < RNUM; ++r) s += AREL[row * 36 + r];
    LSUM[row] = s;
  }
#pragma unroll
  for (int e = 0; e < 4; ++e) {
    float inv = 1.0f / LSUM[w * 16 + lg * 4 + e];
#pragma unroll
    for (int fd = 0; fd < 8; ++fd) oacc[fd][e] *= inv;
  }
  for (int idx = t; idx < 128 * 64; idx += 256) {
    int d = idx >> 6, r = idx & 63;
    u16 v = (r < RNUM) ? f2b(relv[r * DHD + d]) : (u16)0;
    *reinterpret_cast<u16*>(Pb + d * 128 + ((r * 2) ^ ((d & 7) << 4))) = v;
  }
  for (int idx = l; idx < 1024; idx += 64) {
    int ri = idx >> 6, r = idx & 63;
    int row = w * 16 + ri;
    float v = (r < RNUM) ? AREL[row * 36 + r] * (1.0f / LSUM[row]) : 0.f;
    *reinterpret_cast<u16*>(PSw + ri * 128 + ((r * 2) ^ ((ri & 7) << 4))) = f2b(v);
  }
  __syncthreads();              // relvT ready
#pragma unroll
  for (int kc = 0; kc < 2; ++kc) {
    bf16x8 pa = *reinterpret_cast<const bf16x8*>(PSw + ll * 128 + (((kc * 4 + lg) * 16) ^ ((ll & 7) << 4)));
#pragma unroll
    for (int fd = 0; fd < 8; ++fd) {
      int row = fd * 16 + ll;
      bf16x8 vb = *reinterpret_cast<const bf16x8*>(Pb + row * 128 + (((kc * 4 + lg) * 16) ^ ((row & 7) << 4)));
      oacc[fd] = __builtin_amdgcn_mfma_f32_16x16x32_bf16(pa, vb, oacc[fd], 0, 0, 0);
    }
  }
  char* OSw = Qb + w * 4096;
#pragma unroll
  for (int fd = 0; fd < 8; ++fd)
#pragma unroll
    for (int e = 0; e < 4; ++e)
      *reinterpret_cast<u16*>(OSw + ((lg * 4 + e) * 128 + fd * 16 + ll) * 2) = f2b(oacc[fd][e]);
  __syncthreads();
  {
    int ri = l >> 2, q4 = l & 3;
    const char* srcb = OSw + ri * 256 + q4 * 64;
    u16* dst = outb + (size_t)(b * SLEN + i0 + w * 16 + ri) * EDIM + hh * DHD + q4 * 32;
    uint4 x0 = *reinterpret_cast<const uint4*>(srcb);
    uint4 x1 = *reinterpret_cast<const uint4*>(srcb + 16);
    uint4 x2 = *reinterpret_cast<const uint4*>(srcb + 32);
    uint4 x3 = *reinterpret_cast<const uint4*>(srcb + 48);
    *reinterpret_cast<uint4*>(dst)      = x0;
    *reinterpret_cast<uint4*>(dst + 8)  = x1;
    *reinterpret_cast<uint4*>(dst + 16) = x2;
    *reinterpret_cast<uint4*>(dst + 24) = x3;
  }
}

// ---------------- host ----------------
extern "C" void kernel_launch(void* const* d_in, const int* in_sizes, int n_in,
                              void* d_out, int out_size, void* d_ws, size_t ws_size,
                              hipStream_t stream) {
  const float* enc  = (const float*)d_in[0];
  const int*   rel  = (const int*)d_in[1];
  const int*   lens = (const int*)d_in[2];
  const float* Wq = (const float*)d_in[3];
  const float* bq = (const float*)d_in[4];
  const float* Wk = (const float*)d_in[5];
  const float* bk = (const float*)d_in[6];
  const float* Wv = (const float*)d_in[7];
  const float* bv = (const float*)d_in[8];
  const float* Wo = (const float*)d_in[9];
  const float* bo = (const float*)d_in[10];
  const float* relk = (const float*)d_in[11];
  const float* relv = (const float*)d_in[12];
  const float* W1 = (const float*)d_in[13];
  const float* b1 = (const float*)d_in[14];
  const float* W2 = (const float*)d_in[15];
  const float* b2 = (const float*)d_in[16];
  const float* ln1g = (const float*)d_in[17];
  const float* ln1b = (const float*)d_in[18];
  const float* ln2g = (const float*)d_in[19];
  const float* ln2b = (const float*)d_in[20];
  const float* lnfg = (const float*)d_in[21];
  const float* lnfb = (const float*)d_in[22];
  float* out = (float*)d_out;

  char* W = (char*)d_ws;
  u16* h     = (u16*)W;                                // 8 MB (dead during attn)
  unsigned char* rel8_h = (unsigned char*)W;           // fallback: alias of h
  char* U    = W + 8388608;
  u16* qkb   = (u16*)U;                                // 16 MB  [4096][2048]
  u16* vtb   = (u16*)(U + 16777216);                   // 8 MB   [1024][4096]
  u16* attno = (u16*)(U + 25165824);                   // 8 MB   [4096][1024]
  u16* mid   = (u16*)U;                                // 32 MB  (aliases qkb/vtb/attno)
  bool xin = ws_size >= (size_t)83886080;
  float* x = xin ? (float*)(W + 41943040) : out;
  size_t wt_off = xin ? 58720256 : 41943040;
  char* WT = W + wt_off;
  bool big = ws_size >= (size_t)209715200;

  const size_t EE = (size_t)EDIM * EDIM;      // 1M
  const size_t EF = (size_t)EDIM * FFD;       // 4M
  size_t wt_bytes = (big ? 6 : 1) * (size_t)(2*EE + EE + EE + EF + EF) * 2;
  bool rel_ded = ws_size >= wt_off + wt_bytes + (size_t)BNUM * SLEN * SLEN + 256;
  unsigned char* rel8 = rel_ded ? (unsigned char*)(WT + wt_bytes) : rel8_h;

  u16 *WqkT, *WvT, *WoT, *W1T, *W2T;
  dim3 blk(256);
  if (big) {
    u16* wqk_all = (u16*)WT;
    u16* wv_all  = wqk_all + 6 * 2 * EE;
    u16* wo_all  = wv_all + 6 * EE;
    u16* w1_all  = wo_all + 6 * EE;
    u16* w2_all  = w1_all + 6 * EF;
    wtrans<<<dim3(32, 32, 6), blk, 0, stream>>>(Wq, wqk_all, 1024, 1024, EE, 2 * EE);
    wtrans<<<dim3(32, 32, 6), blk, 0, stream>>>(Wk, wqk_all + EE, 1024, 1024, EE, 2 * EE);
    wtrans<<<dim3(32, 32, 6), blk, 0, stream>>>(Wv, wv_all, 1024, 1024, EE, EE);
    wtrans<<<dim3(32, 32, 6), blk, 0, stream>>>(Wo, wo_all, 1024, 1024, EE, EE);
    wtrans<<<dim3(128, 32, 6), blk, 0, stream>>>(W1, w1_all, 1024, 4096, EF, EF);
    wtrans<<<dim3(32, 128, 6), blk, 0, stream>>>(W2, w2_all, 4096, 1024, EF, EF);
    WqkT = wqk_all; WvT = wv_all; WoT = wo_all; W1T = w1_all; W2T = w2_all;
  } else {
    WqkT = (u16*)WT;
    WvT  = WqkT + 2 * EE;
    WoT  = WvT + EE;
    W1T  = WoT + EE;
    W2T  = W1T + EF;
  }
  if (rel_ded) relpack<<<dim3(16, 16, 8), blk, 0, stream>>>(rel, rel8);

  dim3 gLN(TOK);
  for (int ll = 0; ll < LNUM; ++ll) {
    u16 *wqkT, *wvT, *woT, *w1T, *w2T;
    if (big) {
      wqkT = WqkT + (size_t)ll * 2 * EE; wvT = WvT + (size_t)ll * EE; woT = WoT + (size_t)ll * EE;
      w1T = W1T + (size_t)ll * EF; w2T = W2T + (size_t)ll * EF;
    } else {
      wqkT = WqkT; wvT = WvT; woT = WoT; w1T = W1T; w2T = W2T;
      wtrans<<<dim3(32, 32, 1), blk, 0, stream>>>(Wq + ll * EE, wqkT, 1024, 1024, 0, 0);
      wtrans<<<dim3(32, 32, 1), blk, 0, stream>>>(Wk + ll * EE, wqkT + EE, 1024, 1024, 0, 0);
      wtrans<<<dim3(32, 32, 1), blk, 0, stream>>>(Wv + ll * EE, wvT, 1024, 1024, 0, 0);
      wtrans<<<dim3(32, 32, 1), blk, 0, stream>>>(Wo + ll * EE, woT, 1024, 1024, 0, 0);
      wtrans<<<dim3(128, 32, 1), blk, 0, stream>>>(W1 + ll * EF, w1T, 1024, 4096, 0, 0);
      wtrans<<<dim3(32, 128, 1), blk, 0, stream>>>(W2 + ll * EF, w2T, 4096, 1024, 0, 0);
    }
    const float* xin_p = (ll == 0) ? enc : x;
    ln_kernel<1><<<gLN, blk, 0, stream>>>(xin_p, ln1g + ll * EDIM, ln1b + ll * EDIM, h);
    gemm_bt<2, 2, 0, 0, 1><<<dim3(16, 32), blk, 0, stream>>>(h, wqkT, bq + ll * EDIM, bk + ll * EDIM,
                                                             nullptr, qkb, TOK, 2048, EDIM);
    gemm_bt<3, 1, 0, 0, 1><<<dim3(32, 8), blk, 0, stream>>>(wvT, h, bv + ll * EDIM, nullptr,
                                                            nullptr, vtb, EDIM, TOK, EDIM);
    if (!rel_ded) relpack<<<dim3(16, 16, 8), blk, 0, stream>>>(rel, rel8);
    attn_kernel<<<dim3(512), blk, 0, stream>>>(qkb, vtb, rel8, lens,
                                               relk + (size_t)ll * RNUM * DHD,
                                               relv + (size_t)ll * RNUM * DHD, attno);
    gemm_bt<3, 0, 0, 1, 0><<<dim3(8, 32), blk, 0, stream>>>(attno, woT, bo + ll * EDIM, nullptr,
                                                            xin_p, x, TOK, EDIM, EDIM);
    ln_kernel<1><<<gLN, blk, 0, stream>>>(x, ln2g + ll * EDIM, ln2b + ll * EDIM, h);
    gemm_big<0, 1, 0, 1><<<dim3(FFD / 256, TOK / 256), dim3(512), 0, stream>>>(
        h, w1T, b1 + ll * FFD, nullptr, mid, TOK, FFD, EDIM);
    gemm_bt<3, 0, 0, 1, 0><<<dim3(8, 32), blk, 0, stream>>>(mid, w2T, b2 + ll * EDIM, nullptr,
                                                            x, x, TOK, EDIM, FFD);
  }
  ln_kernel<0><<<gLN, blk, 0, stream>>>(x, lnfg, lnfb, out);
}

// Round 18
// 1981.042 us; speedup vs baseline: 1.1136x; 1.0883x over previous
//
#include <hip/hip_runtime.h>

#define LNUM 6
#define EDIM 1024
#define HNUM 8
#define DHD  128
#define RNUM 33
#define FFD  4096
#define BNUM 8
#define SLEN 512
#define TOK  (BNUM*SLEN)   // 4096

typedef __attribute__((ext_vector_type(8))) short bf16x8;
typedef __attribute__((ext_vector_type(4))) float f32x4;
typedef unsigned short u16;
typedef unsigned int u32;

__device__ __forceinline__ u16 f2b(float f) {
  u32 u = __builtin_bit_cast(u32, f);
  u32 r = u + 0x7FFFu + ((u >> 16) & 1u);
  return (u16)(r >> 16);
}
__device__ __forceinline__ u32 pck(float a, float b) { return (u32)f2b(a) | ((u32)f2b(b) << 16); }

// async global->LDS, 16B per lane. LDS dest is wave-uniform base + lane*16.
#define GL16(gp, lp) __builtin_amdgcn_global_load_lds(                        \
    (const __attribute__((address_space(1))) void*)(gp),                      \
    (__attribute__((address_space(3))) void*)(lp), 16, 0, 0)

#define WAITVM20 do { asm volatile("s_waitcnt vmcnt(20)" ::: "memory"); \
                      __builtin_amdgcn_sched_barrier(0); } while (0)
#define WAITVM16 do { asm volatile("s_waitcnt vmcnt(16)" ::: "memory"); \
                      __builtin_amdgcn_sched_barrier(0); } while (0)
#define WAITVM8 do { asm volatile("s_waitcnt vmcnt(8)" ::: "memory"); \
                     __builtin_amdgcn_sched_barrier(0); } while (0)
#define WAITVM0 do { asm volatile("s_waitcnt vmcnt(0)" ::: "memory"); \
                     __builtin_amdgcn_sched_barrier(0); } while (0)

// ---------------- LayerNorm ----------------
template<int BF16OUT>
__global__ __launch_bounds__(256) void ln_kernel(const float* __restrict__ x,
                                                 const float* __restrict__ g,
                                                 const float* __restrict__ be,
                                                 void* __restrict__ o) {
  int row = blockIdx.x;
  int t = threadIdx.x;
  const float* xr = x + (size_t)row * EDIM;
  float4 xv = *reinterpret_cast<const float4*>(xr + t * 4);
  float s1 = xv.x + xv.y + xv.z + xv.w;
  float s2 = xv.x*xv.x + xv.y*xv.y + xv.z*xv.z + xv.w*xv.w;
#pragma unroll
  for (int off = 32; off >= 1; off >>= 1) {
    s1 += __shfl_down(s1, off, 64);
    s2 += __shfl_down(s2, off, 64);
  }
  __shared__ float r1[4], r2[4];
  if ((t & 63) == 0) { r1[t >> 6] = s1; r2[t >> 6] = s2; }
  __syncthreads();
  s1 = r1[0] + r1[1] + r1[2] + r1[3];
  s2 = r2[0] + r2[1] + r2[2] + r2[3];
  float mean = s1 * (1.0f / EDIM);
  float var  = s2 * (1.0f / EDIM) - mean * mean;
  float rstd = rsqrtf(var + 1e-5f);
  float4 gv = *reinterpret_cast<const float4*>(g + t * 4);
  float4 bv = *reinterpret_cast<const float4*>(be + t * 4);
  float o0 = (xv.x - mean) * rstd * gv.x + bv.x;
  float o1 = (xv.y - mean) * rstd * gv.y + bv.y;
  float o2 = (xv.z - mean) * rstd * gv.z + bv.z;
  float o3 = (xv.w - mean) * rstd * gv.w + bv.w;
  if (BF16OUT) {
    ushort4 ov; ov.x = f2b(o0); ov.y = f2b(o1); ov.z = f2b(o2); ov.w = f2b(o3);
    *reinterpret_cast<ushort4*>((u16*)o + (size_t)row * EDIM + t * 4) = ov;
  } else {
    *reinterpret_cast<float4*>((float*)o + (size_t)row * EDIM + t * 4) = make_float4(o0, o1, o2, o3);
  }
}

// ---------------- Weight transpose: f32 [Kd][Nd] -> bf16 [Nd][Kd] ----------------
__global__ __launch_bounds__(256) void wtrans(const float* __restrict__ src0,
                                              u16* __restrict__ dst0,
                                              int Kd, int Nd, size_t sstride, size_t dstride) {
  __shared__ float Ts[32][33];
  const float* src = src0 + blockIdx.z * sstride;
  u16* dst = dst0 + blockIdx.z * dstride;
  int r0 = blockIdx.y * 32, c0 = blockIdx.x * 32;
  int ty = threadIdx.x >> 3, tx = threadIdx.x & 7;
  float4 v = *reinterpret_cast<const float4*>(src + (size_t)(r0 + ty) * Nd + c0 + tx * 4);
  Ts[ty][tx*4+0] = v.x; Ts[ty][tx*4+1] = v.y; Ts[ty][tx*4+2] = v.z; Ts[ty][tx*4+3] = v.w;
  __syncthreads();
  ushort4 o;
  o.x = f2b(Ts[tx*4+0][ty]); o.y = f2b(Ts[tx*4+1][ty]);
  o.z = f2b(Ts[tx*4+2][ty]); o.w = f2b(Ts[tx*4+3][ty]);
  *reinterpret_cast<ushort4*>(dst + (size_t)(c0 + ty) * Kd + r0 + tx * 4) = o;
}

// ---------------- rel pack+transpose: int32 [b][i][j] -> u8 [b][j][i] ----------------
__global__ __launch_bounds__(256) void relpack(const int* __restrict__ rel,
                                               unsigned char* __restrict__ out) {
  __shared__ int Ts[32][33];
  int bz = blockIdx.z;
  int r0 = blockIdx.y * 32, c0 = blockIdx.x * 32;
  int ty = threadIdx.x >> 3, tx = threadIdx.x & 7;
  const int* src = rel + (size_t)bz * SLEN * SLEN;
  int4 v = *reinterpret_cast<const int4*>(src + (size_t)(r0 + ty) * SLEN + c0 + tx * 4);
  Ts[ty][tx*4+0] = v.x; Ts[ty][tx*4+1] = v.y; Ts[ty][tx*4+2] = v.z; Ts[ty][tx*4+3] = v.w;
  __syncthreads();
  u32 o = (u32)(Ts[tx*4+0][ty] & 255) | ((u32)(Ts[tx*4+1][ty] & 255) << 8) |
          ((u32)(Ts[tx*4+2][ty] & 255) << 16) | ((u32)(Ts[tx*4+3][ty] & 255) << 24);
  *reinterpret_cast<u32*>(out + (size_t)bz * SLEN * SLEN + (size_t)(c0 + ty) * SLEN + r0 + tx * 4) = o;
}

// ---------------- bf16 MFMA GEMM 128x128 (256 thr): C = A @ B^T ----------------
// T2 XOR-swizzle both-sides (rule 21): linear LDS dest (gload_lds), source column
// pre-XOR'd with row&7, fragment reads XOR chunk with row&7. Fixes the 16-way
// bank conflict of 128B-stride rows (lanes 0-15 same column -> same 4 banks).
template<int DEPTH, int BIASMODE, int ACT, int RES, int OUTBF16>
__global__ __launch_bounds__(256) void gemm_bt(const u16* __restrict__ A,
                                               const u16* __restrict__ B,
                                               const float* __restrict__ bias0,
                                               const float* __restrict__ bias1,
                                               const float* __restrict__ res,
                                               void* __restrict__ Cv,
                                               int M, int N, int K) {
  __shared__ u16 As[DEPTH][128 * 64];
  __shared__ u16 Bs[DEPTH][128 * 64];
  int t = threadIdx.x;
  int l = t & 63, w = t >> 6;
  int wm = w & 1, wn = w >> 1;
  int m0 = blockIdx.y * 128, n0 = blockIdx.x * 128;
  f32x4 acc[4][4] = {};
  // row within 8-row group = l>>3; source chunk = (l&7) ^ (row&7)  [involution]
  const int sc = (((l & 7) ^ ((l >> 3) & 7))) * 8;
  const u16* Agp = A + (size_t)(m0 + w * 32 + (l >> 3)) * K + sc;
  const u16* Bgp = B + (size_t)(n0 + w * 32 + (l >> 3)) * K + sc;
  const int nst = K >> 6;
  auto issue = [&](int k0, int bi) {
#pragma unroll
    for (int u = 0; u < 4; ++u) {
      GL16(Agp + (size_t)(u * 8) * K + k0, &As[bi][w * 2048 + u * 512]);
      GL16(Bgp + (size_t)(u * 8) * K + k0, &Bs[bi][w * 2048 + u * 512]);
    }
  };
  issue(0, 0);
  if (DEPTH == 3 && nst > 1) issue(64, 1);
  for (int i = 0; i < nst; ++i) {
    int cur = (DEPTH == 3) ? (i % 3) : (i & 1);
    if (DEPTH == 3) {
      if (i + 2 < nst)      { issue((i + 2) * 64, (i + 2) % 3); WAITVM16; }
      else if (i + 1 < nst) { WAITVM8; }
      else                  { WAITVM0; }
    } else {
      if (i + 1 < nst) { issue((i + 1) * 64, cur ^ 1); WAITVM8; }
      else             { WAITVM0; }
    }
    __builtin_amdgcn_s_barrier();
    const u16* Asc = As[cur];
    const u16* Bsc = Bs[cur];
#pragma unroll
    for (int d4 = 0; d4 < 2; ++d4) {
      int c = d4 * 4 + (l >> 4);
      bf16x8 af[4];
#pragma unroll
      for (int fm = 0; fm < 4; ++fm) {
        int row = wm * 64 + fm * 16 + (l & 15);
        af[fm] = *reinterpret_cast<const bf16x8*>(Asc + row * 64 + (c ^ (row & 7)) * 8);
      }
#pragma unroll
      for (int fn = 0; fn < 4; ++fn) {
        int row = wn * 64 + fn * 16 + (l & 15);
        bf16x8 bf = *reinterpret_cast<const bf16x8*>(Bsc + row * 64 + (c ^ (row & 7)) * 8);
#pragma unroll
        for (int fm = 0; fm < 4; ++fm)
          acc[fm][fn] = __builtin_amdgcn_mfma_f32_16x16x32_bf16(af[fm], bf, acc[fm][fn], 0, 0, 0);
      }
    }
    __builtin_amdgcn_s_barrier();
  }
#pragma unroll
  for (int fm = 0; fm < 4; ++fm)
#pragma unroll
    for (int fn = 0; fn < 4; ++fn)
#pragma unroll
      for (int e = 0; e < 4; ++e) {
        int m = m0 + wm * 64 + fm * 16 + (l >> 4) * 4 + e;
        int n = n0 + wn * 64 + fn * 16 + (l & 15);
        float v = acc[fm][fn][e];
        if (BIASMODE == 0) v += bias0[n];
        if (BIASMODE == 1) v += bias0[m];
        if (BIASMODE == 2) v += (n < 1024) ? bias0[n] : bias1[n - 1024];
        if (ACT == 1) v = fmaxf(v, 0.f);
        if (RES == 1) v += res[(size_t)m * N + n];
        if (OUTBF16) ((u16*)Cv)[(size_t)m * N + n] = f2b(v);
        else ((float*)Cv)[(size_t)m * N + n] = v;
      }
}

// ---------------- bf16 MFMA GEMM 256x256 (512 thr, 8 waves 2x4) — FFN1 ----------------
// Same T2 both-sides swizzle as gemm_bt.
template<int BIASMODE, int ACT, int RES, int OUTBF16>
__global__ __launch_bounds__(512, 2) void gemm_big(const u16* __restrict__ A,
                                                   const u16* __restrict__ B,
                                                   const float* __restrict__ bias0,
                                                   const float* __restrict__ res,
                                                   void* __restrict__ Cv,
                                                   int M, int N, int K) {
  __shared__ u16 As[2][256 * 64];
  __shared__ u16 Bs[2][256 * 64];
  int t = threadIdx.x;
  int l = t & 63, w = t >> 6;      // w 0..7
  int wm = w >> 2, wn = w & 3;     // 2 x 4
  int m0 = blockIdx.y * 256, n0 = blockIdx.x * 256;
  f32x4 acc[8][4] = {};
  const int sc = (((l & 7) ^ ((l >> 3) & 7))) * 8;
  const u16* Agp = A + (size_t)(m0 + w * 32 + (l >> 3)) * K + sc;
  const u16* Bgp = B + (size_t)(n0 + w * 32 + (l >> 3)) * K + sc;
  const int nst = K >> 6;
  auto issue = [&](int k0, int bi) {
#pragma unroll
    for (int u = 0; u < 4; ++u) {
      GL16(Agp + (size_t)(u * 8) * K + k0, &As[bi][w * 2048 + u * 512]);
      GL16(Bgp + (size_t)(u * 8) * K + k0, &Bs[bi][w * 2048 + u * 512]);
    }
  };
  issue(0, 0);
  for (int i = 0; i < nst; ++i) {
    int cur = i & 1;
    if (i + 1 < nst) { issue((i + 1) * 64, cur ^ 1); WAITVM8; }
    else             { WAITVM0; }
    __builtin_amdgcn_s_barrier();
    const u16* Asc = As[cur];
    const u16* Bsc = Bs[cur];
#pragma unroll
    for (int d4 = 0; d4 < 2; ++d4) {
      int c = d4 * 4 + (l >> 4);
      bf16x8 bf[4];
#pragma unroll
      for (int fn = 0; fn < 4; ++fn) {
        int row = wn * 64 + fn * 16 + (l & 15);
        bf[fn] = *reinterpret_cast<const bf16x8*>(Bsc + row * 64 + (c ^ (row & 7)) * 8);
      }
#pragma unroll
      for (int fm = 0; fm < 8; ++fm) {
        int row = wm * 128 + fm * 16 + (l & 15);
        bf16x8 af = *reinterpret_cast<const bf16x8*>(Asc + row * 64 + (c ^ (row & 7)) * 8);
#pragma unroll
        for (int fn = 0; fn < 4; ++fn)
          acc[fm][fn] = __builtin_amdgcn_mfma_f32_16x16x32_bf16(af, bf[fn], acc[fm][fn], 0, 0, 0);
      }
    }
    __builtin_amdgcn_s_barrier();
  }
#pragma unroll
  for (int fm = 0; fm < 8; ++fm)
#pragma unroll
    for (int fn = 0; fn < 4; ++fn)
#pragma unroll
      for (int e = 0; e < 4; ++e) {
        int m = m0 + wm * 128 + fm * 16 + (l >> 4) * 4 + e;
        int n = n0 + wn * 64 + fn * 16 + (l & 15);
        float v = acc[fm][fn][e];
        if (BIASMODE == 0) v += bias0[n];
        if (ACT == 1) v = fmaxf(v, 0.f);
        if (RES == 1) v += res[(size_t)m * N + n];
        if (OUTBF16) ((u16*)Cv)[(size_t)m * N + n] = f2b(v);
        else ((float*)Cv)[(size_t)m * N + n] = v;
      }
}

// ---------------- Relational attention (flash, GL16-pipelined, defer-max) ----------
#define A_P  0        // 16384: relk[48][128] swz -> K tile [64][128] swz -> relvT [128][64]
#define A_Q  16384    // 16384: V tile [128 d][64 j] swz -> out-stage [4 waves][16][128]
#define A_PS 32768    // 8192 : per-wave 2048B slabs: P[16][64] swz / arelB [16][64]
#define A_QR 40960    // 9216 : qr f32 [64][36]
#define A_AR 50176    // 9216 : AREL f32 [64][36] (wave-private rows)
#define A_LS 59392    // 256  : LSUM f32 [64]
#define A_SM 59648

__global__ __launch_bounds__(256, 2) void attn_kernel(const u16* __restrict__ qk,
                                                      const u16* __restrict__ vt,
                                                      const unsigned char* __restrict__ rel8,
                                                      const int* __restrict__ lens,
                                                      const float* __restrict__ relk,
                                                      const float* __restrict__ relv,
                                                      u16* __restrict__ outb) {
  __align__(16) __shared__ char sm[A_SM];
  char*  Pb  = sm + A_P;
  char*  Qb  = sm + A_Q;
  char*  PSb = sm + A_PS;
  float* QR  = (float*)(sm + A_QR);
  float* AREL = (float*)(sm + A_AR);
  float* LSUM = (float*)(sm + A_LS);

  const int t = threadIdx.x;
  const int l = t & 63, w = t >> 6;
  const int lg = l >> 4;        // 0..3
  const int ll = l & 15;        // 0..15
  const int bx = blockIdx.x;
  const int xcd = bx & 7, rem = bx >> 3, slot = rem & 7, it = rem >> 3;
  const int g = slot * 8 + xcd;
  const int b = g >> 3, hh = g & 7;
  const int i0 = it * 64;
  const int len = lens[b];
  const float scale = 0.08838834764831845f;
  char* PSw = PSb + w * 2048;

  auto issueK = [&](int kt) {
#pragma unroll
    for (int u = 0; u < 4; ++u) {
      int row = w * 16 + u * 4 + (lg);
      int sb = (ll * 16) ^ (((u * 4 + lg) & 7) << 4);
      const u16* gp = qk + (size_t)(b * SLEN + kt * 64 + row) * 2048 + 1024 + hh * DHD + (sb >> 1);
      GL16(gp, Pb + (w * 4 + u) * 1024);
    }
  };
  auto issueV = [&](int kt) {
#pragma unroll
    for (int u = 0; u < 4; ++u) {
      int row = w * 32 + u * 8 + (l >> 3);
      int sb = ((l & 7) * 16) ^ ((l >> 3) << 4);
      const u16* gp = vt + (size_t)(hh * DHD + row) * TOK + b * SLEN + kt * 64 + (sb >> 1);
      GL16(gp, Qb + (w * 4 + u) * 1024);
    }
  };
  const unsigned char* relbase = rel8 + (size_t)b * SLEN * SLEN + (i0 + w * 16 + lg * 4);

  // ---- prologue ----
  for (int idx = l; idx < 16 * 36; idx += 64) AREL[w * 16 * 36 + idx] = 0.f;
  if (t < 192) {
    int r = t >> 2, sub = t & 3;
#pragma unroll
    for (int u = 0; u < 4; ++u) {
      int seg = sub * 4 + u;
      uint4 o;
      if (r < RNUM) {
        float4 f0 = *reinterpret_cast<const float4*>(relk + r * DHD + seg * 8);
        float4 f1 = *reinterpret_cast<const float4*>(relk + r * DHD + seg * 8 + 4);
        o.x = pck(f0.x, f0.y); o.y = pck(f0.z, f0.w);
        o.z = pck(f1.x, f1.y); o.w = pck(f1.z, f1.w);
      } else { o.x = o.y = o.z = o.w = 0u; }
      *reinterpret_cast<uint4*>(Pb + r * 256 + ((seg * 16) ^ ((r & 7) << 4))) = o;
    }
  }
  bf16x8 aq[4];
  {
    const u16* qrow = qk + (size_t)(b * SLEN + i0 + w * 16 + ll) * 2048 + hh * DHD;
#pragma unroll
    for (int d4 = 0; d4 < 4; ++d4)
      aq[d4] = *reinterpret_cast<const bf16x8*>(qrow + (d4 * 4 + lg) * 8);
  }
  __syncthreads();   // relk staged
#pragma unroll
  for (int rb = 0; rb < 3; ++rb) {
    f32x4 acc = {};
#pragma unroll
    for (int d4 = 0; d4 < 4; ++d4) {
      int rr = rb * 16 + ll;
      bf16x8 br = *reinterpret_cast<const bf16x8*>(Pb + rr * 256 + (((d4 * 4 + lg) * 16) ^ ((rr & 7) << 4)));
      acc = __builtin_amdgcn_mfma_f32_16x16x32_bf16(aq[d4], br, acc, 0, 0, 0);
    }
    int col = rb * 16 + ll;
    if (col < 36)
#pragma unroll
      for (int e = 0; e < 4; ++e)
        QR[(w * 16 + lg * 4 + e) * 36 + col] = acc[e];
  }
  __syncthreads();   // relk reads done; P free (queue empty here)
  issueK(0);         // queue: K0(4)
  u32 relw[4];
  {                  // rel(0) AFTER issueK(0): queue K0(4), rel0(16)
    const unsigned char* rb = relbase + (size_t)ll * SLEN;
#pragma unroll
    for (int fj = 0; fj < 4; ++fj)
      relw[fj] = *reinterpret_cast<const u32*>(rb + (size_t)(fj * 16) * SLEN);
  }

  bool rowv[4];
#pragma unroll
  for (int e = 0; e < 4; ++e) rowv[e] = (i0 + w * 16 + lg * 4 + e) < len;

  float m_[4];
#pragma unroll
  for (int e = 0; e < 4; ++e) m_[e] = -3.0e38f;
  f32x4 oacc[8] = {};

  for (int kt = 0; kt < 8; ++kt) {
    issueV(kt);                 // queue: K(kt)4, rel(kt)16, V(kt)4 = 24
    WAITVM20;                   // retire K(kt) only; rel+V stay in flight
    __builtin_amdgcn_s_barrier();
    __builtin_amdgcn_s_setprio(1);
    f32x4 sacc[4];
#pragma unroll
    for (int fj = 0; fj < 4; ++fj) {
      f32x4 a = {};
#pragma unroll
      for (int d4 = 0; d4 < 4; ++d4) {
        int row = fj * 16 + ll;
        bf16x8 bk_ = *reinterpret_cast<const bf16x8*>(Pb + row * 256 + (((d4 * 4 + lg) * 16) ^ ((row & 7) << 4)));
        a = __builtin_amdgcn_mfma_f32_16x16x32_bf16(aq[d4], bk_, a, 0, 0, 0);
      }
      sacc[fj] = a;
    }
    __builtin_amdgcn_s_setprio(0);
    // fixup (compiler inserts exact vmcnt before relw use; V stays in flight)
#pragma unroll
    for (int fj = 0; fj < 4; ++fj) {
      bool colv = (kt * 64 + fj * 16 + ll) < len;
      u32 rw = relw[fj];
#pragma unroll
      for (int e = 0; e < 4; ++e) {
        int r = (rw >> (8 * e)) & 255;
        float s = (sacc[fj][e] + QR[(w * 16 + lg * 4 + e) * 36 + r]) * scale;
        s = (rowv[e] && colv) ? s : -1e9f;
        sacc[fj][e] = s;
      }
    }
    float pl[4];
#pragma unroll
    for (int e = 0; e < 4; ++e)
      pl[e] = fmaxf(fmaxf(sacc[0][e], sacc[1][e]), fmaxf(sacc[2][e], sacc[3][e]));
    bool ok = (pl[0] <= m_[0] + 8.f) && (pl[1] <= m_[1] + 8.f) &&
              (pl[2] <= m_[2] + 8.f) && (pl[3] <= m_[3] + 8.f);
    if (!__all(ok)) {
#pragma unroll
      for (int e = 0; e < 4; ++e) {
        float px = pl[e];
        px = fmaxf(px, __shfl_xor(px, 1, 64));
        px = fmaxf(px, __shfl_xor(px, 2, 64));
        px = fmaxf(px, __shfl_xor(px, 4, 64));
        px = fmaxf(px, __shfl_xor(px, 8, 64));
        float mn = fmaxf(m_[e], px);
        float f = __expf(m_[e] - mn);
        m_[e] = mn;
#pragma unroll
        for (int fd = 0; fd < 8; ++fd) oacc[fd][e] *= f;
        if (f != 1.0f) {
          int row = w * 16 + lg * 4 + e;
          AREL[row * 36 + ll] *= f;
          AREL[row * 36 + 16 + ll] *= f;
          if (ll == 0) AREL[row * 36 + 32] *= f;
        }
      }
    }
#pragma unroll
    for (int fj = 0; fj < 4; ++fj) {
      u32 rw = relw[fj];
#pragma unroll
      for (int e = 0; e < 4; ++e) {
        float p = __expf(sacc[fj][e] - m_[e]);
        int iloc = lg * 4 + e;
        atomicAdd(&AREL[(w * 16 + iloc) * 36 + ((rw >> (8 * e)) & 255)], p);
        *reinterpret_cast<u16*>(PSw + iloc * 128 + (((fj * 16 + ll) * 2) ^ ((iloc & 7) << 4))) = f2b(p);
      }
    }
    __builtin_amdgcn_s_barrier();   // K(kt) reads done
    if (kt < 7) {
      issueK(kt + 1);               // queue: V(kt)4, K(kt+1)4
      { // rel(kt+1) AFTER issueK: queue V(kt)4, K(kt+1)4, rel(kt+1)16 = 24
        const unsigned char* rb = relbase + (size_t)((kt + 1) * 64 + ll) * SLEN;
#pragma unroll
        for (int fj = 0; fj < 4; ++fj)
          relw[fj] = *reinterpret_cast<const u32*>(rb + (size_t)(fj * 16) * SLEN);
      }
      WAITVM20;                     // retire V(kt) only; K+rel stay in flight
    } else {
      WAITVM0;
    }
    __builtin_amdgcn_s_barrier();
    __builtin_amdgcn_s_setprio(1);
#pragma unroll
    for (int kc = 0; kc < 2; ++kc) {
      bf16x8 pa = *reinterpret_cast<const bf16x8*>(PSw + ll * 128 + (((kc * 4 + lg) * 16) ^ ((ll & 7) << 4)));
#pragma unroll
      for (int fd = 0; fd < 8; ++fd) {
        int row = fd * 16 + ll;
        bf16x8 vb = *reinterpret_cast<const bf16x8*>(Qb + row * 128 + (((kc * 4 + lg) * 16) ^ ((row & 7) << 4)));
        oacc[fd] = __builtin_amdgcn_mfma_f32_16x16x32_bf16(pa, vb, oacc[fd], 0, 0, 0);
      }
    }
    __builtin_amdgcn_s_setprio(0);
    __builtin_amdgcn_s_barrier();   // V(kt) reads done
  }
  // ---- epilogue ----
  if (l < 16) {
    int row = w * 16 + l;
    float s = 0.f;
    for (int r = 0; r < RNUM; ++r) s += AREL[row * 36 + r];
    LSUM[row] = s;
  }
#pragma unroll
  for (int e = 0; e < 4; ++e) {
    float inv = 1.0f / LSUM[w * 16 + lg * 4 + e];
#pragma unroll
    for (int fd = 0; fd < 8; ++fd) oacc[fd][e] *= inv;
  }
  for (int idx = t; idx < 128 * 64; idx += 256) {
    int d = idx >> 6, r = idx & 63;
    u16 v = (r < RNUM) ? f2b(relv[r * DHD + d]) : (u16)0;
    *reinterpret_cast<u16*>(Pb + d * 128 + ((r * 2) ^ ((d & 7) << 4))) = v;
  }
  for (int idx = l; idx < 1024; idx += 64) {
    int ri = idx >> 6, r = idx & 63;
    int row = w * 16 + ri;
    float v = (r < RNUM) ? AREL[row * 36 + r] * (1.0f / LSUM[row]) : 0.f;
    *reinterpret_cast<u16*>(PSw + ri * 128 + ((r * 2) ^ ((ri & 7) << 4))) = f2b(v);
  }
  __syncthreads();              // relvT ready
#pragma unroll
  for (int kc = 0; kc < 2; ++kc) {
    bf16x8 pa = *reinterpret_cast<const bf16x8*>(PSw + ll * 128 + (((kc * 4 + lg) * 16) ^ ((ll & 7) << 4)));
#pragma unroll
    for (int fd = 0; fd < 8; ++fd) {
      int row = fd * 16 + ll;
      bf16x8 vb = *reinterpret_cast<const bf16x8*>(Pb + row * 128 + (((kc * 4 + lg) * 16) ^ ((row & 7) << 4)));
      oacc[fd] = __builtin_amdgcn_mfma_f32_16x16x32_bf16(pa, vb, oacc[fd], 0, 0, 0);
    }
  }
  char* OSw = Qb + w * 4096;
#pragma unroll
  for (int fd = 0; fd < 8; ++fd)
#pragma unroll
    for (int e = 0; e < 4; ++e)
      *reinterpret_cast<u16*>(OSw + ((lg * 4 + e) * 128 + fd * 16 + ll) * 2) = f2b(oacc[fd][e]);
  __syncthreads();
  {
    int ri = l >> 2, q4 = l & 3;
    const char* srcb = OSw + ri * 256 + q4 * 64;
    u16* dst = outb + (size_t)(b * SLEN + i0 + w * 16 + ri) * EDIM + hh * DHD + q4 * 32;
    uint4 x0 = *reinterpret_cast<const uint4*>(srcb);
    uint4 x1 = *reinterpret_cast<const uint4*>(srcb + 16);
    uint4 x2 = *reinterpret_cast<const uint4*>(srcb + 32);
    uint4 x3 = *reinterpret_cast<const uint4*>(srcb + 48);
    *reinterpret_cast<uint4*>(dst)      = x0;
    *reinterpret_cast<uint4*>(dst + 8)  = x1;
    *reinterpret_cast<uint4*>(dst + 16) = x2;
    *reinterpret_cast<uint4*>(dst + 24) = x3;
  }
}

// ---------------- host ----------------
extern "C" void kernel_launch(void* const* d_in, const int* in_sizes, int n_in,
                              void* d_out, int out_size, void* d_ws, size_t ws_size,
                              hipStream_t stream) {
  const float* enc  = (const float*)d_in[0];
  const int*   rel  = (const int*)d_in[1];
  const int*   lens = (const int*)d_in[2];
  const float* Wq = (const float*)d_in[3];
  const float* bq = (const float*)d_in[4];
  const float* Wk = (const float*)d_in[5];
  const float* bk = (const float*)d_in[6];
  const float* Wv = (const float*)d_in[7];
  const float* bv = (const float*)d_in[8];
  const float* Wo = (const float*)d_in[9];
  const float* bo = (const float*)d_in[10];
  const float* relk = (const float*)d_in[11];
  const float* relv = (const float*)d_in[12];
  const float* W1 = (const float*)d_in[13];
  const float* b1 = (const float*)d_in[14];
  const float* W2 = (const float*)d_in[15];
  const float* b2 = (const float*)d_in[16];
  const float* ln1g = (const float*)d_in[17];
  const float* ln1b = (const float*)d_in[18];
  const float* ln2g = (const float*)d_in[19];
  const float* ln2b = (const float*)d_in[20];
  const float* lnfg = (const float*)d_in[21];
  const float* lnfb = (const float*)d_in[22];
  float* out = (float*)d_out;

  char* W = (char*)d_ws;
  u16* h     = (u16*)W;                                // 8 MB (dead during attn)
  unsigned char* rel8_h = (unsigned char*)W;           // fallback: alias of h
  char* U    = W + 8388608;
  u16* qkb   = (u16*)U;                                // 16 MB  [4096][2048]
  u16* vtb   = (u16*)(U + 16777216);                   // 8 MB   [1024][4096]
  u16* attno = (u16*)(U + 25165824);                   // 8 MB   [4096][1024]
  u16* mid   = (u16*)U;                                // 32 MB  (aliases qkb/vtb/attno)
  bool xin = ws_size >= (size_t)83886080;
  float* x = xin ? (float*)(W + 41943040) : out;
  size_t wt_off = xin ? 58720256 : 41943040;
  char* WT = W + wt_off;
  bool big = ws_size >= (size_t)209715200;

  const size_t EE = (size_t)EDIM * EDIM;      // 1M
  const size_t EF = (size_t)EDIM * FFD;       // 4M
  size_t wt_bytes = (big ? 6 : 1) * (size_t)(2*EE + EE + EE + EF + EF) * 2;
  bool rel_ded = ws_size >= wt_off + wt_bytes + (size_t)BNUM * SLEN * SLEN + 256;
  unsigned char* rel8 = rel_ded ? (unsigned char*)(WT + wt_bytes) : rel8_h;

  u16 *WqkT, *WvT, *WoT, *W1T, *W2T;
  dim3 blk(256);
  if (big) {
    u16* wqk_all = (u16*)WT;
    u16* wv_all  = wqk_all + 6 * 2 * EE;
    u16* wo_all  = wv_all + 6 * EE;
    u16* w1_all  = wo_all + 6 * EE;
    u16* w2_all  = w1_all + 6 * EF;
    wtrans<<<dim3(32, 32, 6), blk, 0, stream>>>(Wq, wqk_all, 1024, 1024, EE, 2 * EE);
    wtrans<<<dim3(32, 32, 6), blk, 0, stream>>>(Wk, wqk_all + EE, 1024, 1024, EE, 2 * EE);
    wtrans<<<dim3(32, 32, 6), blk, 0, stream>>>(Wv, wv_all, 1024, 1024, EE, EE);
    wtrans<<<dim3(32, 32, 6), blk, 0, stream>>>(Wo, wo_all, 1024, 1024, EE, EE);
    wtrans<<<dim3(128, 32, 6), blk, 0, stream>>>(W1, w1_all, 1024, 4096, EF, EF);
    wtrans<<<dim3(32, 128, 6), blk, 0, stream>>>(W2, w2_all, 4096, 1024, EF, EF);
    WqkT = wqk_all; WvT = wv_all; WoT = wo_all; W1T = w1_all; W2T = w2_all;
  } else {
    WqkT = (u16*)WT;
    WvT  = WqkT + 2 * EE;
    WoT  = WvT + EE;
    W1T  = WoT + EE;
    W2T  = W1T + EF;
  }
  if (rel_ded) relpack<<<dim3(16, 16, 8), blk, 0, stream>>>(rel, rel8);

  dim3 gLN(TOK);
  for (int ll = 0; ll < LNUM; ++ll) {
    u16 *wqkT, *wvT, *woT, *w1T, *w2T;
    if (big) {
      wqkT = WqkT + (size_t)ll * 2 * EE; wvT = WvT + (size_t)ll * EE; woT = WoT + (size_t)ll * EE;
      w1T = W1T + (size_t)ll * EF; w2T = W2T + (size_t)ll * EF;
    } else {
      wqkT = WqkT; wvT = WvT; woT = WoT; w1T = W1T; w2T = W2T;
      wtrans<<<dim3(32, 32, 1), blk, 0, stream>>>(Wq + ll * EE, wqkT, 1024, 1024, 0, 0);
      wtrans<<<dim3(32, 32, 1), blk, 0, stream>>>(Wk + ll * EE, wqkT + EE, 1024, 1024, 0, 0);
      wtrans<<<dim3(32, 32, 1), blk, 0, stream>>>(Wv + ll * EE, wvT, 1024, 1024, 0, 0);
      wtrans<<<dim3(32, 32, 1), blk, 0, stream>>>(Wo + ll * EE, woT, 1024, 1024, 0, 0);
      wtrans<<<dim3(128, 32, 1), blk, 0, stream>>>(W1 + ll * EF, w1T, 1024, 4096, 0, 0);
      wtrans<<<dim3(32, 128, 1), blk, 0, stream>>>(W2 + ll * EF, w2T, 4096, 1024, 0, 0);
    }
    const float* xin_p = (ll == 0) ? enc : x;
    ln_kernel<1><<<gLN, blk, 0, stream>>>(xin_p, ln1g + ll * EDIM, ln1b + ll * EDIM, h);
    gemm_bt<2, 2, 0, 0, 1><<<dim3(16, 32), blk, 0, stream>>>(h, wqkT, bq + ll * EDIM, bk + ll * EDIM,
                                                             nullptr, qkb, TOK, 2048, EDIM);
    gemm_bt<3, 1, 0, 0, 1><<<dim3(32, 8), blk, 0, stream>>>(wvT, h, bv + ll * EDIM, nullptr,
                                                            nullptr, vtb, EDIM, TOK, EDIM);
    if (!rel_ded) relpack<<<dim3(16, 16, 8), blk, 0, stream>>>(rel, rel8);
    attn_kernel<<<dim3(512), blk, 0, stream>>>(qkb, vtb, rel8, lens,
                                               relk + (size_t)ll * RNUM * DHD,
                                               relv + (size_t)ll * RNUM * DHD, attno);
    gemm_bt<3, 0, 0, 1, 0><<<dim3(8, 32), blk, 0, stream>>>(attno, woT, bo + ll * EDIM, nullptr,
                                                            xin_p, x, TOK, EDIM, EDIM);
    ln_kernel<1><<<gLN, blk, 0, stream>>>(x, ln2g + ll * EDIM, ln2b + ll * EDIM, h);
    gemm_big<0, 1, 0, 1><<<dim3(FFD / 256, TOK / 256), dim3(512), 0, stream>>>(
        h, w1T, b1 + ll * FFD, nullptr, mid, TOK, FFD, EDIM);
    gemm_bt<3, 0, 0, 1, 0><<<dim3(8, 32), blk, 0, stream>>>(mid, w2T, b2 + ll * EDIM, nullptr,
                                                            x, x, TOK, EDIM, FFD);
  }
  ln_kernel<0><<<gLN, blk, 0, stream>>>(x, lnfg, lnfb, out);
}

// Round 19
// 1935.410 us; speedup vs baseline: 1.1399x; 1.0236x over previous
//
#include <hip/hip_runtime.h>

#define LNUM 6
#define EDIM 1024
#define HNUM 8
#define DHD  128
#define RNUM 33
#define FFD  4096
#define BNUM 8
#define SLEN 512
#define TOK  (BNUM*SLEN)   // 4096

typedef __attribute__((ext_vector_type(8))) short bf16x8;
typedef __attribute__((ext_vector_type(4))) float f32x4;
typedef unsigned short u16;
typedef unsigned int u32;

__device__ __forceinline__ u16 f2b(float f) {
  u32 u = __builtin_bit_cast(u32, f);
  u32 r = u + 0x7FFFu + ((u >> 16) & 1u);
  return (u16)(r >> 16);
}
__device__ __forceinline__ u32 pck(float a, float b) { return (u32)f2b(a) | ((u32)f2b(b) << 16); }

// async global->LDS, 16B per lane. LDS dest is wave-uniform base + lane*16.
#define GL16(gp, lp) __builtin_amdgcn_global_load_lds(                        \
    (const __attribute__((address_space(1))) void*)(gp),                      \
    (__attribute__((address_space(3))) void*)(lp), 16, 0, 0)

#define WAITVM20 do { asm volatile("s_waitcnt vmcnt(20)" ::: "memory"); \
                      __builtin_amdgcn_sched_barrier(0); } while (0)
#define WAITVM8 do { asm volatile("s_waitcnt vmcnt(8)" ::: "memory"); \
                     __builtin_amdgcn_sched_barrier(0); } while (0)
#define WAITVM4 do { asm volatile("s_waitcnt vmcnt(4)" ::: "memory"); \
                     __builtin_amdgcn_sched_barrier(0); } while (0)
#define WAITVM0 do { asm volatile("s_waitcnt vmcnt(0)" ::: "memory"); \
                     __builtin_amdgcn_sched_barrier(0); } while (0)

// ---------------- LayerNorm ----------------
template<int BF16OUT>
__global__ __launch_bounds__(256) void ln_kernel(const float* __restrict__ x,
                                                 const float* __restrict__ g,
                                                 const float* __restrict__ be,
                                                 void* __restrict__ o) {
  int row = blockIdx.x;
  int t = threadIdx.x;
  const float* xr = x + (size_t)row * EDIM;
  float4 xv = *reinterpret_cast<const float4*>(xr + t * 4);
  float s1 = xv.x + xv.y + xv.z + xv.w;
  float s2 = xv.x*xv.x + xv.y*xv.y + xv.z*xv.z + xv.w*xv.w;
#pragma unroll
  for (int off = 32; off >= 1; off >>= 1) {
    s1 += __shfl_down(s1, off, 64);
    s2 += __shfl_down(s2, off, 64);
  }
  __shared__ float r1[4], r2[4];
  if ((t & 63) == 0) { r1[t >> 6] = s1; r2[t >> 6] = s2; }
  __syncthreads();
  s1 = r1[0] + r1[1] + r1[2] + r1[3];
  s2 = r2[0] + r2[1] + r2[2] + r2[3];
  float mean = s1 * (1.0f / EDIM);
  float var  = s2 * (1.0f / EDIM) - mean * mean;
  float rstd = rsqrtf(var + 1e-5f);
  float4 gv = *reinterpret_cast<const float4*>(g + t * 4);
  float4 bv = *reinterpret_cast<const float4*>(be + t * 4);
  float o0 = (xv.x - mean) * rstd * gv.x + bv.x;
  float o1 = (xv.y - mean) * rstd * gv.y + bv.y;
  float o2 = (xv.z - mean) * rstd * gv.z + bv.z;
  float o3 = (xv.w - mean) * rstd * gv.w + bv.w;
  if (BF16OUT) {
    ushort4 ov; ov.x = f2b(o0); ov.y = f2b(o1); ov.z = f2b(o2); ov.w = f2b(o3);
    *reinterpret_cast<ushort4*>((u16*)o + (size_t)row * EDIM + t * 4) = ov;
  } else {
    *reinterpret_cast<float4*>((float*)o + (size_t)row * EDIM + t * 4) = make_float4(o0, o1, o2, o3);
  }
}

// ---------------- Weight transpose: f32 [Kd][Nd] -> bf16 [Nd][Kd] ----------------
__global__ __launch_bounds__(256) void wtrans(const float* __restrict__ src0,
                                              u16* __restrict__ dst0,
                                              int Kd, int Nd, size_t sstride, size_t dstride) {
  __shared__ float Ts[32][33];
  const float* src = src0 + blockIdx.z * sstride;
  u16* dst = dst0 + blockIdx.z * dstride;
  int r0 = blockIdx.y * 32, c0 = blockIdx.x * 32;
  int ty = threadIdx.x >> 3, tx = threadIdx.x & 7;
  float4 v = *reinterpret_cast<const float4*>(src + (size_t)(r0 + ty) * Nd + c0 + tx * 4);
  Ts[ty][tx*4+0] = v.x; Ts[ty][tx*4+1] = v.y; Ts[ty][tx*4+2] = v.z; Ts[ty][tx*4+3] = v.w;
  __syncthreads();
  ushort4 o;
  o.x = f2b(Ts[tx*4+0][ty]); o.y = f2b(Ts[tx*4+1][ty]);
  o.z = f2b(Ts[tx*4+2][ty]); o.w = f2b(Ts[tx*4+3][ty]);
  *reinterpret_cast<ushort4*>(dst + (size_t)(c0 + ty) * Kd + r0 + tx * 4) = o;
}

// ---------------- rel pack+transpose: int32 [b][i][j] -> u8 [b][j][i] ----------------
__global__ __launch_bounds__(256) void relpack(const int* __restrict__ rel,
                                               unsigned char* __restrict__ out) {
  __shared__ int Ts[32][33];
  int bz = blockIdx.z;
  int r0 = blockIdx.y * 32, c0 = blockIdx.x * 32;
  int ty = threadIdx.x >> 3, tx = threadIdx.x & 7;
  const int* src = rel + (size_t)bz * SLEN * SLEN;
  int4 v = *reinterpret_cast<const int4*>(src + (size_t)(r0 + ty) * SLEN + c0 + tx * 4);
  Ts[ty][tx*4+0] = v.x; Ts[ty][tx*4+1] = v.y; Ts[ty][tx*4+2] = v.z; Ts[ty][tx*4+3] = v.w;
  __syncthreads();
  u32 o = (u32)(Ts[tx*4+0][ty] & 255) | ((u32)(Ts[tx*4+1][ty] & 255) << 8) |
          ((u32)(Ts[tx*4+2][ty] & 255) << 16) | ((u32)(Ts[tx*4+3][ty] & 255) << 24);
  *reinterpret_cast<u32*>(out + (size_t)bz * SLEN * SLEN + (size_t)(c0 + ty) * SLEN + r0 + tx * 4) = o;
}

// ---------------- bf16 MFMA GEMM 128x128, 512 threads (8 waves 2x4) ----------------
// T2 both-sides swizzle (R18) + 8 waves for 2 waves/SIMD at 1-block/CU dispatches
// (V/O/FFN2) and 4 waves/SIMD for QK (DEPTH2, 64KB, 2 blocks/CU). Conflict-free
// fragment reads make wave-interleave effective (R14's regression was under the
// 16-way-conflict regime). launch_bounds(512,4): VGPR cap 128 (usage ~90).
template<int DEPTH, int BIASMODE, int ACT, int RES, int OUTBF16>
__global__ __launch_bounds__(512, 4) void gemm_bt(const u16* __restrict__ A,
                                                  const u16* __restrict__ B,
                                                  const float* __restrict__ bias0,
                                                  const float* __restrict__ bias1,
                                                  const float* __restrict__ res,
                                                  void* __restrict__ Cv,
                                                  int M, int N, int K) {
  __shared__ u16 As[DEPTH][128 * 64];
  __shared__ u16 Bs[DEPTH][128 * 64];
  int t = threadIdx.x;
  int l = t & 63, w = t >> 6;      // w 0..7
  int wm = w >> 2, wn = w & 3;     // 2 x 4
  int m0 = blockIdx.y * 128, n0 = blockIdx.x * 128;
  f32x4 acc[4][2] = {};
  // staging row = base + l>>3; source chunk = (l&7) ^ (row&7)  [involution]
  const int sc = (((l & 7) ^ ((l >> 3) & 7))) * 8;
  const u16* Agp = A + (size_t)(m0 + w * 16 + (l >> 3)) * K + sc;
  const u16* Bgp = B + (size_t)(n0 + w * 16 + (l >> 3)) * K + sc;
  const int nst = K >> 6;
  auto issue = [&](int k0, int bi) {
#pragma unroll
    for (int u = 0; u < 2; ++u) {
      GL16(Agp + (size_t)(u * 8) * K + k0, &As[bi][w * 1024 + u * 512]);
      GL16(Bgp + (size_t)(u * 8) * K + k0, &Bs[bi][w * 1024 + u * 512]);
    }
  };
  issue(0, 0);
  if (DEPTH == 3 && nst > 1) issue(64, 1);
  for (int i = 0; i < nst; ++i) {
    int cur = (DEPTH == 3) ? (i % 3) : (i & 1);
    if (DEPTH == 3) {
      if (i + 2 < nst)      { issue((i + 2) * 64, (i + 2) % 3); WAITVM8; }
      else if (i + 1 < nst) { WAITVM4; }
      else                  { WAITVM0; }
    } else {
      if (i + 1 < nst) { issue((i + 1) * 64, cur ^ 1); WAITVM4; }
      else             { WAITVM0; }
    }
    __builtin_amdgcn_s_barrier();     // tile i ready everywhere
    const u16* Asc = As[cur];
    const u16* Bsc = Bs[cur];
#pragma unroll
    for (int d4 = 0; d4 < 2; ++d4) {
      int c = d4 * 4 + (l >> 4);
      bf16x8 af[4];
#pragma unroll
      for (int fm = 0; fm < 4; ++fm) {
        int row = wm * 64 + fm * 16 + (l & 15);
        af[fm] = *reinterpret_cast<const bf16x8*>(Asc + row * 64 + (c ^ (row & 7)) * 8);
      }
#pragma unroll
      for (int fn = 0; fn < 2; ++fn) {
        int row = wn * 32 + fn * 16 + (l & 15);
        bf16x8 bf = *reinterpret_cast<const bf16x8*>(Bsc + row * 64 + (c ^ (row & 7)) * 8);
#pragma unroll
        for (int fm = 0; fm < 4; ++fm)
          acc[fm][fn] = __builtin_amdgcn_mfma_f32_16x16x32_bf16(af[fm], bf, acc[fm][fn], 0, 0, 0);
      }
    }
    __builtin_amdgcn_s_barrier();     // tile i reads done (issue may overwrite)
  }
#pragma unroll
  for (int fm = 0; fm < 4; ++fm)
#pragma unroll
    for (int fn = 0; fn < 2; ++fn)
#pragma unroll
      for (int e = 0; e < 4; ++e) {
        int m = m0 + wm * 64 + fm * 16 + (l >> 4) * 4 + e;
        int n = n0 + wn * 32 + fn * 16 + (l & 15);
        float v = acc[fm][fn][e];
        if (BIASMODE == 0) v += bias0[n];
        if (BIASMODE == 1) v += bias0[m];
        if (BIASMODE == 2) v += (n < 1024) ? bias0[n] : bias1[n - 1024];
        if (ACT == 1) v = fmaxf(v, 0.f);
        if (RES == 1) v += res[(size_t)m * N + n];
        if (OUTBF16) ((u16*)Cv)[(size_t)m * N + n] = f2b(v);
        else ((float*)Cv)[(size_t)m * N + n] = v;
      }
}

// ---------------- bf16 MFMA GEMM 256x256 (512 thr, 8 waves 2x4) — FFN1 ----------------
// T2 both-sides swizzle (R18).
template<int BIASMODE, int ACT, int RES, int OUTBF16>
__global__ __launch_bounds__(512, 2) void gemm_big(const u16* __restrict__ A,
                                                   const u16* __restrict__ B,
                                                   const float* __restrict__ bias0,
                                                   const float* __restrict__ res,
                                                   void* __restrict__ Cv,
                                                   int M, int N, int K) {
  __shared__ u16 As[2][256 * 64];
  __shared__ u16 Bs[2][256 * 64];
  int t = threadIdx.x;
  int l = t & 63, w = t >> 6;      // w 0..7
  int wm = w >> 2, wn = w & 3;     // 2 x 4
  int m0 = blockIdx.y * 256, n0 = blockIdx.x * 256;
  f32x4 acc[8][4] = {};
  const int sc = (((l & 7) ^ ((l >> 3) & 7))) * 8;
  const u16* Agp = A + (size_t)(m0 + w * 32 + (l >> 3)) * K + sc;
  const u16* Bgp = B + (size_t)(n0 + w * 32 + (l >> 3)) * K + sc;
  const int nst = K >> 6;
  auto issue = [&](int k0, int bi) {
#pragma unroll
    for (int u = 0; u < 4; ++u) {
      GL16(Agp + (size_t)(u * 8) * K + k0, &As[bi][w * 2048 + u * 512]);
      GL16(Bgp + (size_t)(u * 8) * K + k0, &Bs[bi][w * 2048 + u * 512]);
    }
  };
  issue(0, 0);
  for (int i = 0; i < nst; ++i) {
    int cur = i & 1;
    if (i + 1 < nst) { issue((i + 1) * 64, cur ^ 1); WAITVM8; }
    else             { WAITVM0; }
    __builtin_amdgcn_s_barrier();
    const u16* Asc = As[cur];
    const u16* Bsc = Bs[cur];
#pragma unroll
    for (int d4 = 0; d4 < 2; ++d4) {
      int c = d4 * 4 + (l >> 4);
      bf16x8 bf[4];
#pragma unroll
      for (int fn = 0; fn < 4; ++fn) {
        int row = wn * 64 + fn * 16 + (l & 15);
        bf[fn] = *reinterpret_cast<const bf16x8*>(Bsc + row * 64 + (c ^ (row & 7)) * 8);
      }
#pragma unroll
      for (int fm = 0; fm < 8; ++fm) {
        int row = wm * 128 + fm * 16 + (l & 15);
        bf16x8 af = *reinterpret_cast<const bf16x8*>(Asc + row * 64 + (c ^ (row & 7)) * 8);
#pragma unroll
        for (int fn = 0; fn < 4; ++fn)
          acc[fm][fn] = __builtin_amdgcn_mfma_f32_16x16x32_bf16(af, bf[fn], acc[fm][fn], 0, 0, 0);
      }
    }
    __builtin_amdgcn_s_barrier();
  }
#pragma unroll
  for (int fm = 0; fm < 8; ++fm)
#pragma unroll
    for (int fn = 0; fn < 4; ++fn)
#pragma unroll
      for (int e = 0; e < 4; ++e) {
        int m = m0 + wm * 128 + fm * 16 + (l >> 4) * 4 + e;
        int n = n0 + wn * 64 + fn * 16 + (l & 15);
        float v = acc[fm][fn][e];
        if (BIASMODE == 0) v += bias0[n];
        if (ACT == 1) v = fmaxf(v, 0.f);
        if (RES == 1) v += res[(size_t)m * N + n];
        if (OUTBF16) ((u16*)Cv)[(size_t)m * N + n] = f2b(v);
        else ((float*)Cv)[(size_t)m * N + n] = v;
      }
}

// ---------------- Relational attention (flash, GL16-pipelined, defer-max) ----------
#define A_P  0        // 16384: relk[48][128] swz -> K tile [64][128] swz -> relvT [128][64]
#define A_Q  16384    // 16384: V tile [128 d][64 j] swz -> out-stage [4 waves][16][128]
#define A_PS 32768    // 8192 : per-wave 2048B slabs: P[16][64] swz / arelB [16][64]
#define A_QR 40960    // 9216 : qr f32 [64][36]
#define A_AR 50176    // 9216 : AREL f32 [64][36] (wave-private rows)
#define A_LS 59392    // 256  : LSUM f32 [64]
#define A_SM 59648

__global__ __launch_bounds__(256, 2) void attn_kernel(const u16* __restrict__ qk,
                                                      const u16* __restrict__ vt,
                                                      const unsigned char* __restrict__ rel8,
                                                      const int* __restrict__ lens,
                                                      const float* __restrict__ relk,
                                                      const float* __restrict__ relv,
                                                      u16* __restrict__ outb) {
  __align__(16) __shared__ char sm[A_SM];
  char*  Pb  = sm + A_P;
  char*  Qb  = sm + A_Q;
  char*  PSb = sm + A_PS;
  float* QR  = (float*)(sm + A_QR);
  float* AREL = (float*)(sm + A_AR);
  float* LSUM = (float*)(sm + A_LS);

  const int t = threadIdx.x;
  const int l = t & 63, w = t >> 6;
  const int lg = l >> 4;        // 0..3
  const int ll = l & 15;        // 0..15
  const int bx = blockIdx.x;
  const int xcd = bx & 7, rem = bx >> 3, slot = rem & 7, it = rem >> 3;
  const int g = slot * 8 + xcd;
  const int b = g >> 3, hh = g & 7;
  const int i0 = it * 64;
  const int len = lens[b];
  const float scale = 0.08838834764831845f;
  char* PSw = PSb + w * 2048;

  auto issueK = [&](int kt) {
#pragma unroll
    for (int u = 0; u < 4; ++u) {
      int row = w * 16 + u * 4 + (lg);
      int sb = (ll * 16) ^ (((u * 4 + lg) & 7) << 4);
      const u16* gp = qk + (size_t)(b * SLEN + kt * 64 + row) * 2048 + 1024 + hh * DHD + (sb >> 1);
      GL16(gp, Pb + (w * 4 + u) * 1024);
    }
  };
  auto issueV = [&](int kt) {
#pragma unroll
    for (int u = 0; u < 4; ++u) {
      int row = w * 32 + u * 8 + (l >> 3);
      int sb = ((l & 7) * 16) ^ ((l >> 3) << 4);
      const u16* gp = vt + (size_t)(hh * DHD + row) * TOK + b * SLEN + kt * 64 + (sb >> 1);
      GL16(gp, Qb + (w * 4 + u) * 1024);
    }
  };
  const unsigned char* relbase = rel8 + (size_t)b * SLEN * SLEN + (i0 + w * 16 + lg * 4);

  // ---- prologue ----
  for (int idx = l; idx < 16 * 36; idx += 64) AREL[w * 16 * 36 + idx] = 0.f;
  if (t < 192) {
    int r = t >> 2, sub = t & 3;
#pragma unroll
    for (int u = 0; u < 4; ++u) {
      int seg = sub * 4 + u;
      uint4 o;
      if (r < RNUM) {
        float4 f0 = *reinterpret_cast<const float4*>(relk + r * DHD + seg * 8);
        float4 f1 = *reinterpret_cast<const float4*>(relk + r * DHD + seg * 8 + 4);
        o.x = pck(f0.x, f0.y); o.y = pck(f0.z, f0.w);
        o.z = pck(f1.x, f1.y); o.w = pck(f1.z, f1.w);
      } else { o.x = o.y = o.z = o.w = 0u; }
      *reinterpret_cast<uint4*>(Pb + r * 256 + ((seg * 16) ^ ((r & 7) << 4))) = o;
    }
  }
  bf16x8 aq[4];
  {
    const u16* qrow = qk + (size_t)(b * SLEN + i0 + w * 16 + ll) * 2048 + hh * DHD;
#pragma unroll
    for (int d4 = 0; d4 < 4; ++d4)
      aq[d4] = *reinterpret_cast<const bf16x8*>(qrow + (d4 * 4 + lg) * 8);
  }
  __syncthreads();   // relk staged
#pragma unroll
  for (int rb = 0; rb < 3; ++rb) {
    f32x4 acc = {};
#pragma unroll
    for (int d4 = 0; d4 < 4; ++d4) {
      int rr = rb * 16 + ll;
      bf16x8 br = *reinterpret_cast<const bf16x8*>(Pb + rr * 256 + (((d4 * 4 + lg) * 16) ^ ((rr & 7) << 4)));
      acc = __builtin_amdgcn_mfma_f32_16x16x32_bf16(aq[d4], br, acc, 0, 0, 0);
    }
    int col = rb * 16 + ll;
    if (col < 36)
#pragma unroll
      for (int e = 0; e < 4; ++e)
        QR[(w * 16 + lg * 4 + e) * 36 + col] = acc[e];
  }
  __syncthreads();   // relk reads done; P free (queue empty here)
  issueK(0);         // queue: K0(4)
  u32 relw[4];
  {                  // rel(0) AFTER issueK(0): queue K0(4), rel0(16)
    const unsigned char* rb = relbase + (size_t)ll * SLEN;
#pragma unroll
    for (int fj = 0; fj < 4; ++fj)
      relw[fj] = *reinterpret_cast<const u32*>(rb + (size_t)(fj * 16) * SLEN);
  }

  bool rowv[4];
#pragma unroll
  for (int e = 0; e < 4; ++e) rowv[e] = (i0 + w * 16 + lg * 4 + e) < len;

  float m_[4];
#pragma unroll
  for (int e = 0; e < 4; ++e) m_[e] = -3.0e38f;
  f32x4 oacc[8] = {};

  for (int kt = 0; kt < 8; ++kt) {
    issueV(kt);                 // queue: K(kt)4, rel(kt)16, V(kt)4 = 24
    WAITVM20;                   // retire K(kt) only; rel+V stay in flight
    __builtin_amdgcn_s_barrier();
    __builtin_amdgcn_s_setprio(1);
    f32x4 sacc[4];
#pragma unroll
    for (int fj = 0; fj < 4; ++fj) {
      f32x4 a = {};
#pragma unroll
      for (int d4 = 0; d4 < 4; ++d4) {
        int row = fj * 16 + ll;
        bf16x8 bk_ = *reinterpret_cast<const bf16x8*>(Pb + row * 256 + (((d4 * 4 + lg) * 16) ^ ((row & 7) << 4)));
        a = __builtin_amdgcn_mfma_f32_16x16x32_bf16(aq[d4], bk_, a, 0, 0, 0);
      }
      sacc[fj] = a;
    }
    __builtin_amdgcn_s_setprio(0);
#pragma unroll
    for (int fj = 0; fj < 4; ++fj) {
      bool colv = (kt * 64 + fj * 16 + ll) < len;
      u32 rw = relw[fj];
#pragma unroll
      for (int e = 0; e < 4; ++e) {
        int r = (rw >> (8 * e)) & 255;
        float s = (sacc[fj][e] + QR[(w * 16 + lg * 4 + e) * 36 + r]) * scale;
        s = (rowv[e] && colv) ? s : -1e9f;
        sacc[fj][e] = s;
      }
    }
    float pl[4];
#pragma unroll
    for (int e = 0; e < 4; ++e)
      pl[e] = fmaxf(fmaxf(sacc[0][e], sacc[1][e]), fmaxf(sacc[2][e], sacc[3][e]));
    bool ok = (pl[0] <= m_[0] + 8.f) && (pl[1] <= m_[1] + 8.f) &&
              (pl[2] <= m_[2] + 8.f) && (pl[3] <= m_[3] + 8.f);
    if (!__all(ok)) {
#pragma unroll
      for (int e = 0; e < 4; ++e) {
        float px = pl[e];
        px = fmaxf(px, __shfl_xor(px, 1, 64));
        px = fmaxf(px, __shfl_xor(px, 2, 64));
        px = fmaxf(px, __shfl_xor(px, 4, 64));
        px = fmaxf(px, __shfl_xor(px, 8, 64));
        float mn = fmaxf(m_[e], px);
        float f = __expf(m_[e] - mn);
        m_[e] = mn;
#pragma unroll
        for (int fd = 0; fd < 8; ++fd) oacc[fd][e] *= f;
        if (f != 1.0f) {
          int row = w * 16 + lg * 4 + e;
          AREL[row * 36 + ll] *= f;
          AREL[row * 36 + 16 + ll] *= f;
          if (ll == 0) AREL[row * 36 + 32] *= f;
        }
      }
    }
#pragma unroll
    for (int fj = 0; fj < 4; ++fj) {
      u32 rw = relw[fj];
#pragma unroll
      for (int e = 0; e < 4; ++e) {
        float p = __expf(sacc[fj][e] - m_[e]);
        int iloc = lg * 4 + e;
        atomicAdd(&AREL[(w * 16 + iloc) * 36 + ((rw >> (8 * e)) & 255)], p);
        *reinterpret_cast<u16*>(PSw + iloc * 128 + (((fj * 16 + ll) * 2) ^ ((iloc & 7) << 4))) = f2b(p);
      }
    }
    __builtin_amdgcn_s_barrier();   // K(kt) reads done
    if (kt < 7) {
      issueK(kt + 1);               // queue: V(kt)4, K(kt+1)4
      {
        const unsigned char* rb = relbase + (size_t)((kt + 1) * 64 + ll) * SLEN;
#pragma unroll
        for (int fj = 0; fj < 4; ++fj)
          relw[fj] = *reinterpret_cast<const u32*>(rb + (size_t)(fj * 16) * SLEN);
      }
      WAITVM20;                     // retire V(kt) only; K+rel stay in flight
    } else {
      WAITVM0;
    }
    __builtin_amdgcn_s_barrier();
    __builtin_amdgcn_s_setprio(1);
#pragma unroll
    for (int kc = 0; kc < 2; ++kc) {
      bf16x8 pa = *reinterpret_cast<const bf16x8*>(PSw + ll * 128 + (((kc * 4 + lg) * 16) ^ ((ll & 7) << 4)));
#pragma unroll
      for (int fd = 0; fd < 8; ++fd) {
        int row = fd * 16 + ll;
        bf16x8 vb = *reinterpret_cast<const bf16x8*>(Qb + row * 128 + (((kc * 4 + lg) * 16) ^ ((row & 7) << 4)));
        oacc[fd] = __builtin_amdgcn_mfma_f32_16x16x32_bf16(pa, vb, oacc[fd], 0, 0, 0);
      }
    }
    __builtin_amdgcn_s_setprio(0);
    __builtin_amdgcn_s_barrier();   // V(kt) reads done
  }
  // ---- epilogue ----
  if (l < 16) {
    int row = w * 16 + l;
    float s = 0.f;
    for (int r = 0; r < RNUM; ++r) s += AREL[row * 36 + r];
    LSUM[row] = s;
  }
#pragma unroll
  for (int e = 0; e < 4; ++e) {
    float inv = 1.0f / LSUM[w * 16 + lg * 4 + e];
#pragma unroll
    for (int fd = 0; fd < 8; ++fd) oacc[fd][e] *= inv;
  }
  for (int idx = t; idx < 128 * 64; idx += 256) {
    int d = idx >> 6, r = idx & 63;
    u16 v = (r < RNUM) ? f2b(relv[r * DHD + d]) : (u16)0;
    *reinterpret_cast<u16*>(Pb + d * 128 + ((r * 2) ^ ((d & 7) << 4))) = v;
  }
  for (int idx = l; idx < 1024; idx += 64) {
    int ri = idx >> 6, r = idx & 63;
    int row = w * 16 + ri;
    float v = (r < RNUM) ? AREL[row * 36 + r] * (1.0f / LSUM[row]) : 0.f;
    *reinterpret_cast<u16*>(PSw + ri * 128 + ((r * 2) ^ ((ri & 7) << 4))) = f2b(v);
  }
  __syncthreads();              // relvT ready
#pragma unroll
  for (int kc = 0; kc < 2; ++kc) {
    bf16x8 pa = *reinterpret_cast<const bf16x8*>(PSw + ll * 128 + (((kc * 4 + lg) * 16) ^ ((ll & 7) << 4)));
#pragma unroll
    for (int fd = 0; fd < 8; ++fd) {
      int row = fd * 16 + ll;
      bf16x8 vb = *reinterpret_cast<const bf16x8*>(Pb + row * 128 + (((kc * 4 + lg) * 16) ^ ((row & 7) << 4)));
      oacc[fd] = __builtin_amdgcn_mfma_f32_16x16x32_bf16(pa, vb, oacc[fd], 0, 0, 0);
    }
  }
  char* OSw = Qb + w * 4096;
#pragma unroll
  for (int fd = 0; fd < 8; ++fd)
#pragma unroll
    for (int e = 0; e < 4; ++e)
      *reinterpret_cast<u16*>(OSw + ((lg * 4 + e) * 128 + fd * 16 + ll) * 2) = f2b(oacc[fd][e]);
  __syncthreads();
  {
    int ri = l >> 2, q4 = l & 3;
    const char* srcb = OSw + ri * 256 + q4 * 64;
    u16* dst = outb + (size_t)(b * SLEN + i0 + w * 16 + ri) * EDIM + hh * DHD + q4 * 32;
    uint4 x0 = *reinterpret_cast<const uint4*>(srcb);
    uint4 x1 = *reinterpret_cast<const uint4*>(srcb + 16);
    uint4 x2 = *reinterpret_cast<const uint4*>(srcb + 32);
    uint4 x3 = *reinterpret_cast<const uint4*>(srcb + 48);
    *reinterpret_cast<uint4*>(dst)      = x0;
    *reinterpret_cast<uint4*>(dst + 8)  = x1;
    *reinterpret_cast<uint4*>(dst + 16) = x2;
    *reinterpret_cast<uint4*>(dst + 24) = x3;
  }
}

// ---------------- host ----------------
extern "C" void kernel_launch(void* const* d_in, const int* in_sizes, int n_in,
                              void* d_out, int out_size, void* d_ws, size_t ws_size,
                              hipStream_t stream) {
  const float* enc  = (const float*)d_in[0];
  const int*   rel  = (const int*)d_in[1];
  const int*   lens = (const int*)d_in[2];
  const float* Wq = (const float*)d_in[3];
  const float* bq = (const float*)d_in[4];
  const float* Wk = (const float*)d_in[5];
  const float* bk = (const float*)d_in[6];
  const float* Wv = (const float*)d_in[7];
  const float* bv = (const float*)d_in[8];
  const float* Wo = (const float*)d_in[9];
  const float* bo = (const float*)d_in[10];
  const float* relk = (const float*)d_in[11];
  const float* relv = (const float*)d_in[12];
  const float* W1 = (const float*)d_in[13];
  const float* b1 = (const float*)d_in[14];
  const float* W2 = (const float*)d_in[15];
  const float* b2 = (const float*)d_in[16];
  const float* ln1g = (const float*)d_in[17];
  const float* ln1b = (const float*)d_in[18];
  const float* ln2g = (const float*)d_in[19];
  const float* ln2b = (const float*)d_in[20];
  const float* lnfg = (const float*)d_in[21];
  const float* lnfb = (const float*)d_in[22];
  float* out = (float*)d_out;

  char* W = (char*)d_ws;
  u16* h     = (u16*)W;                                // 8 MB (dead during attn)
  unsigned char* rel8_h = (unsigned char*)W;           // fallback: alias of h
  char* U    = W + 8388608;
  u16* qkb   = (u16*)U;                                // 16 MB  [4096][2048]
  u16* vtb   = (u16*)(U + 16777216);                   // 8 MB   [1024][4096]
  u16* attno = (u16*)(U + 25165824);                   // 8 MB   [4096][1024]
  u16* mid   = (u16*)U;                                // 32 MB  (aliases qkb/vtb/attno)
  bool xin = ws_size >= (size_t)83886080;
  float* x = xin ? (float*)(W + 41943040) : out;
  size_t wt_off = xin ? 58720256 : 41943040;
  char* WT = W + wt_off;
  bool big = ws_size >= (size_t)209715200;

  const size_t EE = (size_t)EDIM * EDIM;      // 1M
  const size_t EF = (size_t)EDIM * FFD;       // 4M
  size_t wt_bytes = (big ? 6 : 1) * (size_t)(2*EE + EE + EE + EF + EF) * 2;
  bool rel_ded = ws_size >= wt_off + wt_bytes + (size_t)BNUM * SLEN * SLEN + 256;
  unsigned char* rel8 = rel_ded ? (unsigned char*)(WT + wt_bytes) : rel8_h;

  u16 *WqkT, *WvT, *WoT, *W1T, *W2T;
  dim3 blk(256);
  if (big) {
    u16* wqk_all = (u16*)WT;
    u16* wv_all  = wqk_all + 6 * 2 * EE;
    u16* wo_all  = wv_all + 6 * EE;
    u16* w1_all  = wo_all + 6 * EE;
    u16* w2_all  = w1_all + 6 * EF;
    wtrans<<<dim3(32, 32, 6), blk, 0, stream>>>(Wq, wqk_all, 1024, 1024, EE, 2 * EE);
    wtrans<<<dim3(32, 32, 6), blk, 0, stream>>>(Wk, wqk_all + EE, 1024, 1024, EE, 2 * EE);
    wtrans<<<dim3(32, 32, 6), blk, 0, stream>>>(Wv, wv_all, 1024, 1024, EE, EE);
    wtrans<<<dim3(32, 32, 6), blk, 0, stream>>>(Wo, wo_all, 1024, 1024, EE, EE);
    wtrans<<<dim3(128, 32, 6), blk, 0, stream>>>(W1, w1_all, 1024, 4096, EF, EF);
    wtrans<<<dim3(32, 128, 6), blk, 0, stream>>>(W2, w2_all, 4096, 1024, EF, EF);
    WqkT = wqk_all; WvT = wv_all; WoT = wo_all; W1T = w1_all; W2T = w2_all;
  } else {
    WqkT = (u16*)WT;
    WvT  = WqkT + 2 * EE;
    WoT  = WvT + EE;
    W1T  = WoT + EE;
    W2T  = W1T + EF;
  }
  if (rel_ded) relpack<<<dim3(16, 16, 8), blk, 0, stream>>>(rel, rel8);

  dim3 gLN(TOK);
  for (int ll = 0; ll < LNUM; ++ll) {
    u16 *wqkT, *wvT, *woT, *w1T, *w2T;
    if (big) {
      wqkT = WqkT + (size_t)ll * 2 * EE; wvT = WvT + (size_t)ll * EE; woT = WoT + (size_t)ll * EE;
      w1T = W1T + (size_t)ll * EF; w2T = W2T + (size_t)ll * EF;
    } else {
      wqkT = WqkT; wvT = WvT; woT = WoT; w1T = W1T; w2T = W2T;
      wtrans<<<dim3(32, 32, 1), blk, 0, stream>>>(Wq + ll * EE, wqkT, 1024, 1024, 0, 0);
      wtrans<<<dim3(32, 32, 1), blk, 0, stream>>>(Wk + ll * EE, wqkT + EE, 1024, 1024, 0, 0);
      wtrans<<<dim3(32, 32, 1), blk, 0, stream>>>(Wv + ll * EE, wvT, 1024, 1024, 0, 0);
      wtrans<<<dim3(32, 32, 1), blk, 0, stream>>>(Wo + ll * EE, woT, 1024, 1024, 0, 0);
      wtrans<<<dim3(128, 32, 1), blk, 0, stream>>>(W1 + ll * EF, w1T, 1024, 4096, 0, 0);
      wtrans<<<dim3(32, 128, 1), blk, 0, stream>>>(W2 + ll * EF, w2T, 4096, 1024, 0, 0);
    }
    const float* xin_p = (ll == 0) ? enc : x;
    ln_kernel<1><<<gLN, blk, 0, stream>>>(xin_p, ln1g + ll * EDIM, ln1b + ll * EDIM, h);
    gemm_bt<2, 2, 0, 0, 1><<<dim3(16, 32), dim3(512), 0, stream>>>(
        h, wqkT, bq + ll * EDIM, bk + ll * EDIM, nullptr, qkb, TOK, 2048, EDIM);
    gemm_bt<3, 1, 0, 0, 1><<<dim3(32, 8), dim3(512), 0, stream>>>(
        wvT, h, bv + ll * EDIM, nullptr, nullptr, vtb, EDIM, TOK, EDIM);
    if (!rel_ded) relpack<<<dim3(16, 16, 8), blk, 0, stream>>>(rel, rel8);
    attn_kernel<<<dim3(512), blk, 0, stream>>>(qkb, vtb, rel8, lens,
                                               relk + (size_t)ll * RNUM * DHD,
                                               relv + (size_t)ll * RNUM * DHD, attno);
    gemm_bt<3, 0, 0, 1, 0><<<dim3(8, 32), dim3(512), 0, stream>>>(
        attno, woT, bo + ll * EDIM, nullptr, xin_p, x, TOK, EDIM, EDIM);
    ln_kernel<1><<<gLN, blk, 0, stream>>>(x, ln2g + ll * EDIM, ln2b + ll * EDIM, h);
    gemm_big<0, 1, 0, 1><<<dim3(FFD / 256, TOK / 256), dim3(512), 0, stream>>>(
        h, w1T, b1 + ll * FFD, nullptr, mid, TOK, FFD, EDIM);
    gemm_bt<3, 0, 0, 1, 0><<<dim3(8, 32), dim3(512), 0, stream>>>(
        mid, w2T, b2 + ll * EDIM, nullptr, x, x, TOK, EDIM, FFD);
  }
  ln_kernel<0><<<gLN, blk, 0, stream>>>(x, lnfg, lnfb, out);
}